// Round 14
// baseline (190.608 us; speedup 1.0000x reference)
//
#include <hip/hip_runtime.h>

using u16   = unsigned short;
using f32x4 = __attribute__((ext_vector_type(4))) float;
using s16x8 = __attribute__((ext_vector_type(8))) short;
using s16x4 = __attribute__((ext_vector_type(4))) short;

#define DEVI static __device__ __forceinline__

DEVI float b2f(u16 u){ union{unsigned int i; float f;} v; v.i = ((unsigned int)u)<<16; return v.f; }
DEVI u16 f2b(float f){ union{float f; unsigned int i;} v; v.f = f;
  unsigned int r = v.i + 0x7fffu + ((v.i>>16)&1u); return (u16)(r>>16); }

// hardware bf16 convert (clang lowers to v_cvt_pk_bf16_f32 on gfx950, RNE)
DEVI short f2bs(float f){
  __bf16 h = (__bf16)f;
  short s;
  __builtin_memcpy(&s, &h, 2);
  return s;
}

// raw v_exp_f32 (no denorm-fixup sequence); inputs here are bounded |x|<~8
#if __has_builtin(__builtin_amdgcn_exp2f)
#define EXP2(x) __builtin_amdgcn_exp2f(x)
#else
#define EXP2(x) __builtin_exp2f(x)
#endif

DEVI f32x4 mfma16(s16x8 a, s16x8 b, f32x4 c){
  return __builtin_amdgcn_mfma_f32_16x16x32_bf16(a, b, c, 0, 0, 0);
}

constexpr int   HH     = 104;
constexpr int   NTOK   = 10816;          // 104*104
constexpr float SLOG2E = 0.0625f * 1.44269504088896340736f;  // SCALE * log2(e)
constexpr float RSCALE = 0.0625f;        // 256^-0.5

// ---- workspace layout (bytes) ----
constexpr size_t OFF_WQKVT = 0x0000000;  // 768*256 bf16
constexpr size_t OFF_WOT   = 0x0060000;  // 256*256 bf16
constexpr size_t OFF_LWT   = 0x0080000;  // 49*256 f32
constexpr size_t OFF_QBF   = 0x0090000;  // 2*10816*256 bf16 (0xA90000)
constexpr size_t OFF_KBF   = 0x0B20000;
constexpr size_t OFF_VBF   = 0x15B0000;
constexpr size_t OFF_VWT   = 0x2040000;  // v window-transposed+kappa-permuted [2][169][256][64] bf16
constexpr size_t OFF_QWIN  = 0x2AD0000;  // f32 [2][169][256]
constexpr size_t OFF_KWIN  = 0x2B25000;
constexpr size_t OFF_RIDX  = 0x2B7A000;  // int [2][169][10]
constexpr size_t OFF_XBF   = 0x2B7E000;  // bf16 x copy (11 MB)
constexpr size_t OFF_AO    = 0x360E000;  // bf16 fused attn+lepe [2][10816][256]
constexpr size_t OFF_LEPE  = 0x409E000;  // bf16 lepe
constexpr size_t WS_NEEDED = 0x55BE000;  // ~86 MB

// ---------------- kernel 0: weight transposes (fp32 -> bf16, lepe_w fp32) ----------------
__global__ void k_prep(const float* __restrict__ Wqkv, const float* __restrict__ Wo,
                       const float* __restrict__ lw,
                       u16* __restrict__ wqkvT, u16* __restrict__ woT, float* __restrict__ lwT){
  int id = blockIdx.x*256 + threadIdx.x;
  if (id < 768*256){
    int n = id >> 8, k = id & 255;
    wqkvT[id] = f2b(Wqkv[k*768 + n]);
  } else if (id < 768*256 + 256*256){
    int o = id - 768*256; int n = o >> 8, k = o & 255;
    woT[o] = f2b(Wo[k*256 + n]);
  } else {
    int o = id - (768*256 + 256*256); int t = o >> 8, c = o & 255;
    lwT[o] = lw[c*49 + t];
  }
}

// ---------------- kernel 1: QKV GEMM (xbf @ Wqkv + b); q pre-scaled by SCALE*log2e ----------------
__global__ __launch_bounds__(256) void k_qkv(const u16* __restrict__ xbf, const u16* __restrict__ wT,
    const float* __restrict__ bias,
    u16* __restrict__ qb, u16* __restrict__ kb, u16* __restrict__ vb){
  __shared__ __align__(16) short As[128][72];
  __shared__ __align__(16) short Bs[128][72];
  const int m0 = blockIdx.x*128, n0 = blockIdx.y*128;
  const int tid = threadIdx.x, wv = tid>>6, l = tid&63;
  const int wm = (wv>>1)*64, wn = (wv&1)*64;
  const int l15 = l&15, lh = l>>4;
  f32x4 acc[4][4];
  #pragma unroll
  for (int mf=0;mf<4;mf++)
    #pragma unroll
    for (int nf=0;nf<4;nf++) acc[mf][nf] = (f32x4){0.f,0.f,0.f,0.f};

  for (int kk=0; kk<256; kk+=64){
    __syncthreads();
    #pragma unroll
    for (int i=0;i<4;i++){
      int sid = i*256 + tid; int r = sid>>3, cu = (sid&7)*8;
      *(s16x8*)&As[r][cu] = *(const s16x8*)(xbf + (size_t)(m0+r)*256 + kk + cu);
      *(s16x8*)&Bs[r][cu] = *(const s16x8*)(wT  + (size_t)(n0+r)*256 + kk + cu);
    }
    __syncthreads();
    #pragma unroll
    for (int ks=0; ks<2; ks++){
      s16x8 af[4], bf[4];
      #pragma unroll
      for (int mf=0; mf<4; mf++) af[mf] = *(const s16x8*)&As[wm+mf*16+l15][ks*32 + lh*8];
      #pragma unroll
      for (int nf=0; nf<4; nf++) bf[nf] = *(const s16x8*)&Bs[wn+nf*16+l15][ks*32 + lh*8];
      #pragma unroll
      for (int mf=0; mf<4; mf++)
        #pragma unroll
        for (int nf=0; nf<4; nf++)
          acc[mf][nf] = mfma16(af[mf], bf[nf], acc[mf][nf]);
    }
  }
  const int sec = n0 >> 8;  // 0:q 1:k 2:v
  u16* dst = sec==0 ? qb : (sec==1 ? kb : vb);
  const float qsc = (sec==0) ? SLOG2E : 1.f;
  #pragma unroll
  for (int mf=0; mf<4; mf++)
    #pragma unroll
    for (int nf=0; nf<4; nf++){
      int gcol = n0 + wn + nf*16 + l15;
      int ccol = gcol & 255;
      float bsv = bias[gcol];
      #pragma unroll
      for (int r=0;r<4;r++){
        int row = m0 + wm + mf*16 + lh*4 + r;
        dst[(size_t)row*256 + ccol] = f2b((acc[mf][nf][r] + bsv)*qsc);
      }
    }
}

// ---------------- kernel 2: fp32 window means of x -> q_win/k_win; also emits bf16 x copy ----
__global__ __launch_bounds__(256) void k_winproj(const float* __restrict__ x,
    const float* __restrict__ Wqkv, const float* __restrict__ bqkv,
    float* __restrict__ qwin, float* __restrict__ kwin, u16* __restrict__ xbf){
  int bp = blockIdx.x; int b = bp/169, p = bp%169;
  int wy = p/13, wx = p%13;
  __shared__ float xm[256];
  int c = threadIdx.x;
  float s = 0.f;
  for (int w=0; w<64; w++){
    int n = (wy*8 + (w>>3))*HH + wx*8 + (w&7);
    size_t off = ((size_t)b*NTOK + n)*256 + c;
    float xv = x[off];
    s += xv;
    xbf[off] = (u16)f2bs(xv);
  }
  xm[c] = s * (1.f/64.f);
  __syncthreads();
  float sq = bqkv[c], sk = bqkv[256 + c];
  #pragma unroll 4
  for (int k=0; k<256; k++){
    float xv = xm[k];
    sq += xv * Wqkv[k*768 + c];
    sk += xv * Wqkv[k*768 + 256 + c];
  }
  qwin[(size_t)bp*256 + c] = sq;
  kwin[(size_t)bp*256 + c] = sk;
}

// ---------------- kernel 3: per-window transpose of v, columns in kappa-permuted key order ----
// slot cw holds V[key]: key = cw5*32 + cw2*16 + cw4*8 + cw3*4 + (cw&3)
__global__ void k_vt(const u16* __restrict__ vb, u16* __restrict__ vwt){
  int blk = blockIdx.x; int bp = blk>>2, ct = blk&3;
  int b = bp/169, p = bp%169;
  int wy = p/13, wx = p%13; int c0 = ct*64;
  __shared__ __align__(16) short L[64][72];
  int tid = threadIdx.x;
  #pragma unroll
  for (int i=0;i<2;i++){
    int sid = i*256 + tid; int r = sid>>3, cu = (sid&7)*8;
    int n = (wy*8 + (r>>3))*HH + wx*8 + (r&7);
    *(s16x8*)&L[r][cu] = *(const s16x8*)(vb + ((size_t)b*NTOK + n)*256 + c0 + cu);
  }
  __syncthreads();
  #pragma unroll
  for (int i=0;i<2;i++){
    int oid = i*256 + tid; int c = oid>>3, wu = (oid&7)*8;
    s16x8 vv;
    #pragma unroll
    for (int j=0;j<8;j++){
      int cw = wu + j;
      int wsrc = ((cw>>5)&1)*32 + ((cw>>2)&1)*16 + ((cw>>4)&1)*8 + ((cw>>3)&1)*4 + (cw&3);
      vv[j] = L[wsrc][c];
    }
    *(s16x8*)(vwt + (size_t)bp*16384 + (size_t)(c0+c)*64 + wu) = vv;
  }
}

// ---------------- kernel 4: router logits + top-10 ----------------
__global__ void k_router(const float* __restrict__ qwin, const float* __restrict__ kwin,
                         int* __restrict__ ridx){
  int bp = blockIdx.x; int b = bp/169;
  __shared__ float qs[256];
  __shared__ float lg[176];
  int tid = threadIdx.x, wv = tid>>6, l = tid&63;
  qs[tid] = qwin[(size_t)bp*256 + tid] * RSCALE;
  __syncthreads();
  const float* kbase = kwin + (size_t)b*169*256;
  for (int q = wv; q < 169; q += 4){
    float s = 0.f;
    #pragma unroll
    for (int j=0;j<4;j++) s += qs[l + 64*j] * kbase[(size_t)q*256 + l + 64*j];
    #pragma unroll
    for (int d=32; d; d>>=1) s += __shfl_xor(s, d);
    if (l == 0) lg[q] = s;
  }
  __syncthreads();
  if (wv == 0){
    for (int t=0;t<10;t++){
      float bv = -1e30f; int bi = 0;
      for (int q=l; q<169; q+=64){
        float v = lg[q];
        if (v > bv || (v == bv && q < bi)){ bv = v; bi = q; }
      }
      #pragma unroll
      for (int d=32; d; d>>=1){
        float ov = __shfl_xor(bv, d); int oi = __shfl_xor(bi, d);
        if (ov > bv || (ov == bv && oi < bi)){ bv = ov; bi = oi; }
      }
      if (l == 0){ ridx[bp*10 + t] = bi; lg[bi] = -1e30f; }
    }
  }
}

// ---------------- kernel 5: LEPE depthwise 7x7, LDS-tiled 8x8x64, bf16 out ----------------
__global__ __launch_bounds__(256) void k_conv(const u16* __restrict__ vb, const float* __restrict__ lwT,
                       const float* __restrict__ lb, u16* __restrict__ lepe){
  __shared__ float Lp[196*64];  // 50176 B
  const int blk = blockIdx.x;
  const int cg = blk & 3; int t = blk >> 2;
  const int tx = t % 13; int t2 = t / 13;
  const int ty = t2 % 13; const int b = t2 / 13;
  const int c0 = cg*64;
  const int tid = threadIdx.x;
  const int lane8 = tid & 7;
  #pragma unroll
  for (int i=0;i<7;i++){
    int sid = i*256 + tid;
    int pp = sid >> 3;
    if (pp < 196){
      int py = pp/14, px = pp - py*14;
      int gy = ty*8 + py - 3, gx = tx*8 + px - 3;
      f32x4 v0 = (f32x4){0.f,0.f,0.f,0.f}, v1 = (f32x4){0.f,0.f,0.f,0.f};
      if ((unsigned)gy < (unsigned)HH && (unsigned)gx < (unsigned)HH){
        s16x8 v = *(const s16x8*)(vb + ((size_t)b*NTOK + gy*HH + gx)*256 + c0 + lane8*8);
        v0[0]=b2f((u16)v[0]); v0[1]=b2f((u16)v[1]); v0[2]=b2f((u16)v[2]); v0[3]=b2f((u16)v[3]);
        v1[0]=b2f((u16)v[4]); v1[1]=b2f((u16)v[5]); v1[2]=b2f((u16)v[6]); v1[3]=b2f((u16)v[7]);
      }
      float* dst = &Lp[pp*64 + lane8*8];
      *(f32x4*)dst = v0;
      *(f32x4*)(dst+4) = v1;
    }
  }
  const int c = tid & 63;
  const int yg = tid >> 6;  // 0..3
  float w[49];
  #pragma unroll
  for (int kt=0; kt<49; kt++) w[kt] = lwT[kt*256 + c0 + c];
  const float bias = lb[c0 + c];
  __syncthreads();
  #pragma unroll
  for (int half=0; half<2; half++){
    const int y = yg + half*4;
    float acc[8];
    #pragma unroll
    for (int xx=0;xx<8;xx++) acc[xx] = bias;
    #pragma unroll
    for (int ky=0;ky<7;ky++){
      const int prow = (y + ky)*14;
      float rv[14];
      #pragma unroll
      for (int xx=0;xx<14;xx++) rv[xx] = Lp[(prow + xx)*64 + c];
      #pragma unroll
      for (int kx=0;kx<7;kx++){
        float wv = w[ky*7+kx];
        #pragma unroll
        for (int xx=0;xx<8;xx++) acc[xx] = fmaf(wv, rv[xx+kx], acc[xx]);
      }
    }
    const int gy = ty*8 + y;
    size_t base = ((size_t)b*NTOK + gy*HH + tx*8)*256 + c0 + c;
    #pragma unroll
    for (int xx=0;xx<8;xx++) lepe[base + (size_t)xx*256] = f2b(acc[xx]);
  }
}

// ---------------- kernel 6: attention, 2-way query split, ZERO LDS, raw v_exp_f32 ----------------
// Wave handles query-frags {qh*2, qh*2+1} over ALL windows (full softmax per query in-wave,
// no combine). 5408 waves total. Swapped QK^T + kappa-permuted V as before.
__global__ __launch_bounds__(64, 4) void k_attn(const u16* __restrict__ qb, const u16* __restrict__ kb,
    const u16* __restrict__ vwt, const int* __restrict__ ridx,
    const u16* __restrict__ lepe, u16* __restrict__ ao){
  const int blk = blockIdx.x;
  const int qh = blk & 1, h = (blk>>1) & 7, bp = blk >> 4;
  const int b = bp/169, p = bp%169;
  const int wy = p/13, wx = p%13;
  const int l = threadIdx.x, l15 = l&15, lh = l>>4;
  const int rowoff = (l15>>3)*HH + (l15&7);

  s16x8 qf[2];
  {
    const u16* qbase = qb + ((size_t)b*NTOK + (wy*8)*HH + wx*8 + rowoff)*256 + h*32 + lh*8
                          + (size_t)(qh*2)*2*HH*256;
    qf[0] = *(const s16x8*)(qbase);
    qf[1] = *(const s16x8*)(qbase + (size_t)2*HH*256);
  }
  f32x4 o[2][2];
  f32x4 lsum4[2];
  #pragma unroll
  for (int m=0;m<2;m++){
    o[m][0] = (f32x4){0.f,0.f,0.f,0.f};
    o[m][1] = (f32x4){0.f,0.f,0.f,0.f};
    lsum4[m] = (f32x4){0.f,0.f,0.f,0.f};
  }

  const int* rp = ridx + bp*10;
  int win = rp[0];
  for (int t=0;t<10;t++){
    int wnext = (t<9) ? rp[t+1] : 0;     // prefetch next window index (off-chain)
    if ((unsigned)win > 168u) win = 0;
    int vy = win/13, vx = win - vy*13;
    const u16* kbase = kb + ((size_t)b*NTOK + (vy*8)*HH + vx*8 + rowoff)*256 + h*32 + lh*8;
    s16x8 kf[4];
    #pragma unroll
    for (int nf=0;nf<4;nf++) kf[nf] = *(const s16x8*)(kbase + (size_t)nf*2*HH*256);
    const u16* vbase = vwt + ((size_t)(b*169 + win)*256 + h*32 + l15)*64 + lh*8;
    s16x8 vf[2][2];
    #pragma unroll
    for (int d=0;d<2;d++)
      #pragma unroll
      for (int ks=0;ks<2;ks++)
        vf[d][ks] = *(const s16x8*)(vbase + d*1024 + ks*32);

    #pragma unroll
    for (int m=0;m<2;m++){
      f32x4 s0 = mfma16(kf[0], qf[m], (f32x4){0.f,0.f,0.f,0.f});
      f32x4 s1 = mfma16(kf[1], qf[m], (f32x4){0.f,0.f,0.f,0.f});
      f32x4 s2 = mfma16(kf[2], qf[m], (f32x4){0.f,0.f,0.f,0.f});
      f32x4 s3 = mfma16(kf[3], qf[m], (f32x4){0.f,0.f,0.f,0.f});
      f32x4 e0, e1, e2, e3;
      #pragma unroll
      for (int j=0;j<4;j++){
        e0[j] = EXP2(s0[j]);
        e1[j] = EXP2(s1[j]);
        e2[j] = EXP2(s2[j]);
        e3[j] = EXP2(s3[j]);
      }
      lsum4[m] += (e0+e1)+(e2+e3);
      s16x8 p0, p1;
      #pragma unroll
      for (int j=0;j<4;j++){
        p0[j]   = f2bs(e0[j]);
        p0[4+j] = f2bs(e1[j]);
        p1[j]   = f2bs(e2[j]);
        p1[4+j] = f2bs(e3[j]);
      }
      o[m][0] = mfma16(p0, vf[0][0], o[m][0]);
      o[m][0] = mfma16(p1, vf[0][1], o[m][0]);
      o[m][1] = mfma16(p0, vf[1][0], o[m][1]);
      o[m][1] = mfma16(p1, vf[1][1], o[m][1]);
    }
    win = wnext;
  }
  // epilogue: lane holds denom partial for query (qh*2+m)*16+l15; outputs are query lh*4+r
  #pragma unroll
  for (int m=0;m<2;m++){
    int mf = qh*2 + m;
    float tot = (lsum4[m][0]+lsum4[m][1]) + (lsum4[m][2]+lsum4[m][3]);
    tot += __shfl_xor(tot,16);
    tot += __shfl_xor(tot,32);
    #pragma unroll
    for (int r=0;r<4;r++){
      float inv = 1.f/__shfl(tot, lh*4+r);
      int qr = mf*16 + lh*4 + r;
      int n = (wy*8 + (qr>>3))*HH + wx*8 + (qr&7);
      size_t base = ((size_t)b*NTOK + n)*256 + h*32;
      ao[base +      l15] = (u16)f2bs(o[m][0][r]*inv + b2f(lepe[base +      l15]));
      ao[base + 16 + l15] = (u16)f2bs(o[m][1][r]*inv + b2f(lepe[base + 16 + l15]));
    }
  }
}

// ---------------- kernel 7: out = ao @ Wo + bo ----------------
__global__ __launch_bounds__(256) void k_final(const u16* __restrict__ ao,
    const u16* __restrict__ woT, const float* __restrict__ bo, float* __restrict__ out){
  __shared__ __align__(16) short As[128][72];
  __shared__ __align__(16) short Bs[128][72];
  const int m0 = blockIdx.x*128, n0 = blockIdx.y*128;
  const int tid = threadIdx.x, wv = tid>>6, l = tid&63;
  const int wm = (wv>>1)*64, wn = (wv&1)*64;
  const int l15 = l&15, lh = l>>4;
  f32x4 acc[4][4];
  #pragma unroll
  for (int mf=0;mf<4;mf++)
    #pragma unroll
    for (int nf=0;nf<4;nf++) acc[mf][nf] = (f32x4){0.f,0.f,0.f,0.f};

  for (int kk=0; kk<256; kk+=64){
    __syncthreads();
    #pragma unroll
    for (int i=0;i<4;i++){
      int sid = i*256 + tid; int r = sid>>3, cu = (sid&7)*8;
      *(s16x8*)&As[r][cu] = *(const s16x8*)(ao  + (size_t)(m0+r)*256 + kk + cu);
      *(s16x8*)&Bs[r][cu] = *(const s16x8*)(woT + (size_t)(n0+r)*256 + kk + cu);
    }
    __syncthreads();
    #pragma unroll
    for (int ks=0; ks<2; ks++){
      s16x8 af[4], bf[4];
      #pragma unroll
      for (int mf=0; mf<4; mf++) af[mf] = *(const s16x8*)&As[wm+mf*16+l15][ks*32 + lh*8];
      #pragma unroll
      for (int nf=0; nf<4; nf++) bf[nf] = *(const s16x8*)&Bs[wn+nf*16+l15][ks*32 + lh*8];
      #pragma unroll
      for (int mf=0; mf<4; mf++)
        #pragma unroll
        for (int nf=0; nf<4; nf++)
          acc[mf][nf] = mfma16(af[mf], bf[nf], acc[mf][nf]);
    }
  }
  #pragma unroll
  for (int mf=0; mf<4; mf++)
    #pragma unroll
    for (int nf=0; nf<4; nf++){
      int gcol = n0 + wn + nf*16 + l15;
      float bv = bo[gcol];
      #pragma unroll
      for (int r=0;r<4;r++){
        int row = m0 + wm + mf*16 + lh*4 + r;
        out[(size_t)row*256 + gcol] = acc[mf][nf][r] + bv;
      }
    }
}

extern "C" void kernel_launch(void* const* d_in, const int* in_sizes, int n_in,
                              void* d_out, int out_size, void* d_ws, size_t ws_size,
                              hipStream_t stream){
  (void)in_sizes; (void)n_in; (void)out_size;
  if (ws_size < WS_NEEDED) return;
  const float* x    = (const float*)d_in[0];
  const float* Wqkv = (const float*)d_in[1];
  const float* bqkv = (const float*)d_in[2];
  const float* Wo   = (const float*)d_in[3];
  const float* bo   = (const float*)d_in[4];
  const float* lw   = (const float*)d_in[5];
  const float* lb   = (const float*)d_in[6];
  char* ws = (char*)d_ws;
  u16*   wqkvT = (u16*)(ws + OFF_WQKVT);
  u16*   woT   = (u16*)(ws + OFF_WOT);
  float* lwT   = (float*)(ws + OFF_LWT);
  u16*   qbf   = (u16*)(ws + OFF_QBF);
  u16*   kbf   = (u16*)(ws + OFF_KBF);
  u16*   vbf   = (u16*)(ws + OFF_VBF);
  u16*   vwt   = (u16*)(ws + OFF_VWT);
  float* qwin  = (float*)(ws + OFF_QWIN);
  float* kwin  = (float*)(ws + OFF_KWIN);
  int*   ridx  = (int*)(ws + OFF_RIDX);
  u16*   xbf   = (u16*)(ws + OFF_XBF);
  u16*   ao    = (u16*)(ws + OFF_AO);
  u16*   lepe  = (u16*)(ws + OFF_LEPE);
  float* out   = (float*)d_out;

  k_prep   <<<1073, 256, 0, stream>>>(Wqkv, Wo, lw, wqkvT, woT, lwT);
  k_winproj<<<338, 256, 0, stream>>>(x, Wqkv, bqkv, qwin, kwin, xbf);
  k_qkv    <<<dim3(169,6), 256, 0, stream>>>(xbf, wqkvT, bqkv, qbf, kbf, vbf);
  k_vt     <<<1352, 256, 0, stream>>>(vbf, vwt);
  k_router <<<338, 256, 0, stream>>>(qwin, kwin, ridx);
  k_conv   <<<1352, 256, 0, stream>>>(vbf, lwT, lb, lepe);
  k_attn   <<<5408, 64, 0, stream>>>(qbf, kbf, vwt, ridx, lepe, ao);
  k_final  <<<dim3(169,2), 256, 0, stream>>>(ao, woT, bo, out);
}

// Round 15
// 183.052 us; speedup vs baseline: 1.0413x; 1.0413x over previous
//
#include <hip/hip_runtime.h>

using u16   = unsigned short;
using f32x4 = __attribute__((ext_vector_type(4))) float;
using s16x8 = __attribute__((ext_vector_type(8))) short;
using s16x4 = __attribute__((ext_vector_type(4))) short;

#define DEVI static __device__ __forceinline__

DEVI float b2f(u16 u){ union{unsigned int i; float f;} v; v.i = ((unsigned int)u)<<16; return v.f; }
DEVI u16 f2b(float f){ union{float f; unsigned int i;} v; v.f = f;
  unsigned int r = v.i + 0x7fffu + ((v.i>>16)&1u); return (u16)(r>>16); }

// hardware bf16 convert (clang lowers to v_cvt_pk_bf16_f32 on gfx950, RNE)
DEVI short f2bs(float f){
  __bf16 h = (__bf16)f;
  short s;
  __builtin_memcpy(&s, &h, 2);
  return s;
}

// raw v_exp_f32 (no denorm-fixup sequence); inputs here are bounded |x|<~8
#if __has_builtin(__builtin_amdgcn_exp2f)
#define EXP2(x) __builtin_amdgcn_exp2f(x)
#else
#define EXP2(x) __builtin_exp2f(x)
#endif

DEVI f32x4 mfma16(s16x8 a, s16x8 b, f32x4 c){
  return __builtin_amdgcn_mfma_f32_16x16x32_bf16(a, b, c, 0, 0, 0);
}

constexpr int   HH     = 104;
constexpr int   NTOK   = 10816;          // 104*104
constexpr float SLOG2E = 0.0625f * 1.44269504088896340736f;  // SCALE * log2(e)
constexpr float RSCALE = 0.0625f;        // 256^-0.5

// ---- workspace layout (bytes) ----
constexpr size_t OFF_WQKVT = 0x0000000;  // 768*256 bf16
constexpr size_t OFF_WOT   = 0x0060000;  // 256*256 bf16
constexpr size_t OFF_LWT   = 0x0080000;  // 49*256 f32
constexpr size_t OFF_QBF   = 0x0090000;  // 2*10816*256 bf16 (0xA90000)
constexpr size_t OFF_KBF   = 0x0B20000;
constexpr size_t OFF_VBF   = 0x15B0000;
constexpr size_t OFF_VWT   = 0x2040000;  // v window-transposed+kappa-permuted [2][169][256][64] bf16
constexpr size_t OFF_QWIN  = 0x2AD0000;  // f32 [2][169][256]
constexpr size_t OFF_KWIN  = 0x2B25000;
constexpr size_t OFF_RIDX  = 0x2B7A000;  // int [2][169][10]
constexpr size_t OFF_XBF   = 0x2B7E000;  // bf16 x copy (11 MB)
constexpr size_t OFF_AO    = 0x360E000;  // bf16 fused attn+lepe [2][10816][256]
constexpr size_t OFF_LEPE  = 0x409E000;  // bf16 lepe
constexpr size_t WS_NEEDED = 0x55BE000;  // ~86 MB

// ---------------- kernel 0: weight transposes (fp32 -> bf16, lepe_w fp32) ----------------
__global__ void k_prep(const float* __restrict__ Wqkv, const float* __restrict__ Wo,
                       const float* __restrict__ lw,
                       u16* __restrict__ wqkvT, u16* __restrict__ woT, float* __restrict__ lwT){
  int id = blockIdx.x*256 + threadIdx.x;
  if (id < 768*256){
    int n = id >> 8, k = id & 255;
    wqkvT[id] = f2b(Wqkv[k*768 + n]);
  } else if (id < 768*256 + 256*256){
    int o = id - 768*256; int n = o >> 8, k = o & 255;
    woT[o] = f2b(Wo[k*256 + n]);
  } else {
    int o = id - (768*256 + 256*256); int t = o >> 8, c = o & 255;
    lwT[o] = lw[c*49 + t];
  }
}

// ---------------- kernel 1: QKV GEMM (xbf @ Wqkv + b); q pre-scaled by SCALE*log2e ----------------
__global__ __launch_bounds__(256) void k_qkv(const u16* __restrict__ xbf, const u16* __restrict__ wT,
    const float* __restrict__ bias,
    u16* __restrict__ qb, u16* __restrict__ kb, u16* __restrict__ vb){
  __shared__ __align__(16) short As[128][72];
  __shared__ __align__(16) short Bs[128][72];
  const int m0 = blockIdx.x*128, n0 = blockIdx.y*128;
  const int tid = threadIdx.x, wv = tid>>6, l = tid&63;
  const int wm = (wv>>1)*64, wn = (wv&1)*64;
  const int l15 = l&15, lh = l>>4;
  f32x4 acc[4][4];
  #pragma unroll
  for (int mf=0;mf<4;mf++)
    #pragma unroll
    for (int nf=0;nf<4;nf++) acc[mf][nf] = (f32x4){0.f,0.f,0.f,0.f};

  for (int kk=0; kk<256; kk+=64){
    __syncthreads();
    #pragma unroll
    for (int i=0;i<4;i++){
      int sid = i*256 + tid; int r = sid>>3, cu = (sid&7)*8;
      *(s16x8*)&As[r][cu] = *(const s16x8*)(xbf + (size_t)(m0+r)*256 + kk + cu);
      *(s16x8*)&Bs[r][cu] = *(const s16x8*)(wT  + (size_t)(n0+r)*256 + kk + cu);
    }
    __syncthreads();
    #pragma unroll
    for (int ks=0; ks<2; ks++){
      s16x8 af[4], bf[4];
      #pragma unroll
      for (int mf=0; mf<4; mf++) af[mf] = *(const s16x8*)&As[wm+mf*16+l15][ks*32 + lh*8];
      #pragma unroll
      for (int nf=0; nf<4; nf++) bf[nf] = *(const s16x8*)&Bs[wn+nf*16+l15][ks*32 + lh*8];
      #pragma unroll
      for (int mf=0; mf<4; mf++)
        #pragma unroll
        for (int nf=0; nf<4; nf++)
          acc[mf][nf] = mfma16(af[mf], bf[nf], acc[mf][nf]);
    }
  }
  const int sec = n0 >> 8;  // 0:q 1:k 2:v
  u16* dst = sec==0 ? qb : (sec==1 ? kb : vb);
  const float qsc = (sec==0) ? SLOG2E : 1.f;
  #pragma unroll
  for (int mf=0; mf<4; mf++)
    #pragma unroll
    for (int nf=0; nf<4; nf++){
      int gcol = n0 + wn + nf*16 + l15;
      int ccol = gcol & 255;
      float bsv = bias[gcol];
      #pragma unroll
      for (int r=0;r<4;r++){
        int row = m0 + wm + mf*16 + lh*4 + r;
        dst[(size_t)row*256 + ccol] = f2b((acc[mf][nf][r] + bsv)*qsc);
      }
    }
}

// ---------------- kernel 2: fp32 window means of x -> q_win/k_win; also emits bf16 x copy ----
__global__ __launch_bounds__(256) void k_winproj(const float* __restrict__ x,
    const float* __restrict__ Wqkv, const float* __restrict__ bqkv,
    float* __restrict__ qwin, float* __restrict__ kwin, u16* __restrict__ xbf){
  int bp = blockIdx.x; int b = bp/169, p = bp%169;
  int wy = p/13, wx = p%13;
  __shared__ float xm[256];
  int c = threadIdx.x;
  float s = 0.f;
  for (int w=0; w<64; w++){
    int n = (wy*8 + (w>>3))*HH + wx*8 + (w&7);
    size_t off = ((size_t)b*NTOK + n)*256 + c;
    float xv = x[off];
    s += xv;
    xbf[off] = (u16)f2bs(xv);
  }
  xm[c] = s * (1.f/64.f);
  __syncthreads();
  float sq = bqkv[c], sk = bqkv[256 + c];
  #pragma unroll 4
  for (int k=0; k<256; k++){
    float xv = xm[k];
    sq += xv * Wqkv[k*768 + c];
    sk += xv * Wqkv[k*768 + 256 + c];
  }
  qwin[(size_t)bp*256 + c] = sq;
  kwin[(size_t)bp*256 + c] = sk;
}

// ---------------- kernel 3: per-window transpose of v, columns in kappa-permuted key order ----
// slot cw holds V[key]: key = cw5*32 + cw2*16 + cw4*8 + cw3*4 + (cw&3)
__global__ void k_vt(const u16* __restrict__ vb, u16* __restrict__ vwt){
  int blk = blockIdx.x; int bp = blk>>2, ct = blk&3;
  int b = bp/169, p = bp%169;
  int wy = p/13, wx = p%13; int c0 = ct*64;
  __shared__ __align__(16) short L[64][72];
  int tid = threadIdx.x;
  #pragma unroll
  for (int i=0;i<2;i++){
    int sid = i*256 + tid; int r = sid>>3, cu = (sid&7)*8;
    int n = (wy*8 + (r>>3))*HH + wx*8 + (r&7);
    *(s16x8*)&L[r][cu] = *(const s16x8*)(vb + ((size_t)b*NTOK + n)*256 + c0 + cu);
  }
  __syncthreads();
  #pragma unroll
  for (int i=0;i<2;i++){
    int oid = i*256 + tid; int c = oid>>3, wu = (oid&7)*8;
    s16x8 vv;
    #pragma unroll
    for (int j=0;j<8;j++){
      int cw = wu + j;
      int wsrc = ((cw>>5)&1)*32 + ((cw>>2)&1)*16 + ((cw>>4)&1)*8 + ((cw>>3)&1)*4 + (cw&3);
      vv[j] = L[wsrc][c];
    }
    *(s16x8*)(vwt + (size_t)bp*16384 + (size_t)(c0+c)*64 + wu) = vv;
  }
}

// ---------------- kernel 4: router logits + top-10 ----------------
__global__ void k_router(const float* __restrict__ qwin, const float* __restrict__ kwin,
                         int* __restrict__ ridx){
  int bp = blockIdx.x; int b = bp/169;
  __shared__ float qs[256];
  __shared__ float lg[176];
  int tid = threadIdx.x, wv = tid>>6, l = tid&63;
  qs[tid] = qwin[(size_t)bp*256 + tid] * RSCALE;
  __syncthreads();
  const float* kbase = kwin + (size_t)b*169*256;
  for (int q = wv; q < 169; q += 4){
    float s = 0.f;
    #pragma unroll
    for (int j=0;j<4;j++) s += qs[l + 64*j] * kbase[(size_t)q*256 + l + 64*j];
    #pragma unroll
    for (int d=32; d; d>>=1) s += __shfl_xor(s, d);
    if (l == 0) lg[q] = s;
  }
  __syncthreads();
  if (wv == 0){
    for (int t=0;t<10;t++){
      float bv = -1e30f; int bi = 0;
      for (int q=l; q<169; q+=64){
        float v = lg[q];
        if (v > bv || (v == bv && q < bi)){ bv = v; bi = q; }
      }
      #pragma unroll
      for (int d=32; d; d>>=1){
        float ov = __shfl_xor(bv, d); int oi = __shfl_xor(bi, d);
        if (ov > bv || (ov == bv && oi < bi)){ bv = ov; bi = oi; }
      }
      if (l == 0){ ridx[bp*10 + t] = bi; lg[bi] = -1e30f; }
    }
  }
}

// ---------------- kernel 5: LEPE depthwise 7x7, LDS-tiled 8x8x64, bf16 out ----------------
__global__ __launch_bounds__(256) void k_conv(const u16* __restrict__ vb, const float* __restrict__ lwT,
                       const float* __restrict__ lb, u16* __restrict__ lepe){
  __shared__ float Lp[196*64];  // 50176 B
  const int blk = blockIdx.x;
  const int cg = blk & 3; int t = blk >> 2;
  const int tx = t % 13; int t2 = t / 13;
  const int ty = t2 % 13; const int b = t2 / 13;
  const int c0 = cg*64;
  const int tid = threadIdx.x;
  const int lane8 = tid & 7;
  #pragma unroll
  for (int i=0;i<7;i++){
    int sid = i*256 + tid;
    int pp = sid >> 3;
    if (pp < 196){
      int py = pp/14, px = pp - py*14;
      int gy = ty*8 + py - 3, gx = tx*8 + px - 3;
      f32x4 v0 = (f32x4){0.f,0.f,0.f,0.f}, v1 = (f32x4){0.f,0.f,0.f,0.f};
      if ((unsigned)gy < (unsigned)HH && (unsigned)gx < (unsigned)HH){
        s16x8 v = *(const s16x8*)(vb + ((size_t)b*NTOK + gy*HH + gx)*256 + c0 + lane8*8);
        v0[0]=b2f((u16)v[0]); v0[1]=b2f((u16)v[1]); v0[2]=b2f((u16)v[2]); v0[3]=b2f((u16)v[3]);
        v1[0]=b2f((u16)v[4]); v1[1]=b2f((u16)v[5]); v1[2]=b2f((u16)v[6]); v1[3]=b2f((u16)v[7]);
      }
      float* dst = &Lp[pp*64 + lane8*8];
      *(f32x4*)dst = v0;
      *(f32x4*)(dst+4) = v1;
    }
  }
  const int c = tid & 63;
  const int yg = tid >> 6;  // 0..3
  float w[49];
  #pragma unroll
  for (int kt=0; kt<49; kt++) w[kt] = lwT[kt*256 + c0 + c];
  const float bias = lb[c0 + c];
  __syncthreads();
  #pragma unroll
  for (int half=0; half<2; half++){
    const int y = yg + half*4;
    float acc[8];
    #pragma unroll
    for (int xx=0;xx<8;xx++) acc[xx] = bias;
    #pragma unroll
    for (int ky=0;ky<7;ky++){
      const int prow = (y + ky)*14;
      float rv[14];
      #pragma unroll
      for (int xx=0;xx<14;xx++) rv[xx] = Lp[(prow + xx)*64 + c];
      #pragma unroll
      for (int kx=0;kx<7;kx++){
        float wv = w[ky*7+kx];
        #pragma unroll
        for (int xx=0;xx<8;xx++) acc[xx] = fmaf(wv, rv[xx+kx], acc[xx]);
      }
    }
    const int gy = ty*8 + y;
    size_t base = ((size_t)b*NTOK + gy*HH + tx*8)*256 + c0 + c;
    #pragma unroll
    for (int xx=0;xx<8;xx++) lepe[base + (size_t)xx*256] = f2b(acc[xx]);
  }
}

// ---------------- kernel 6: attention, 1 wave/block, ZERO LDS, rolling dbuf (unroll 1) ----------
// Swapped QK^T (S^T = mfma(K,Q)) -> lane holds 16 P-values for ONE query (keys nf*16+lh*4+r).
// With vwt's kappa permutation those 16 values ARE the lane's two PV A-fragments.
// 2-deep rolling K/V register buffers; loop NOT unrolled so only 2 windows stay in flight
// (R12's full unroll hoisted all 10 windows' loads -> spill).
__global__ __launch_bounds__(64, 2) void k_attn(const u16* __restrict__ qb, const u16* __restrict__ kb,
    const u16* __restrict__ vwt, const int* __restrict__ ridx,
    const u16* __restrict__ lepe, u16* __restrict__ ao){
  const int blk = blockIdx.x;
  const int h = blk & 7, bp = blk >> 3;
  const int b = bp/169, p = bp%169;
  const int wy = p/13, wx = p%13;
  const int l = threadIdx.x, l15 = l&15, lh = l>>4;
  const int rowoff = (l15>>3)*HH + (l15&7);

  s16x8 qf[4];
  {
    const u16* qbase = qb + ((size_t)b*NTOK + (wy*8)*HH + wx*8 + rowoff)*256 + h*32 + lh*8;
    #pragma unroll
    for (int mf=0;mf<4;mf++) qf[mf] = *(const s16x8*)(qbase + (size_t)mf*2*HH*256);
  }
  f32x4 o[4][2];
  f32x4 lsum4[4];
  #pragma unroll
  for (int mf=0;mf<4;mf++){
    o[mf][0] = (f32x4){0.f,0.f,0.f,0.f};
    o[mf][1] = (f32x4){0.f,0.f,0.f,0.f};
    lsum4[mf] = (f32x4){0.f,0.f,0.f,0.f};
  }

  const int* rp = ridx + bp*10;

#define LOADW(KF, VF, WIN) do { \
    int vy_ = (WIN)/13, vx_ = (WIN) - vy_*13; \
    const u16* kb_ = kb + ((size_t)b*NTOK + (vy_*8)*HH + vx_*8 + rowoff)*256 + h*32 + lh*8; \
    KF[0] = *(const s16x8*)(kb_); \
    KF[1] = *(const s16x8*)(kb_ + (size_t)2*HH*256); \
    KF[2] = *(const s16x8*)(kb_ + (size_t)4*HH*256); \
    KF[3] = *(const s16x8*)(kb_ + (size_t)6*HH*256); \
    const u16* vb_ = vwt + ((size_t)(b*169 + (WIN))*256 + h*32 + l15)*64 + lh*8; \
    VF[0][0] = *(const s16x8*)(vb_); \
    VF[0][1] = *(const s16x8*)(vb_ + 32); \
    VF[1][0] = *(const s16x8*)(vb_ + 1024); \
    VF[1][1] = *(const s16x8*)(vb_ + 1056); \
  } while(0)

#define COMPW(KF, VF) do { \
    _Pragma("unroll") \
    for (int mf=0;mf<4;mf++){ \
      f32x4 zz = (f32x4){0.f,0.f,0.f,0.f}; \
      f32x4 s0 = mfma16(KF[0], qf[mf], zz); \
      f32x4 s1 = mfma16(KF[1], qf[mf], zz); \
      f32x4 s2 = mfma16(KF[2], qf[mf], zz); \
      f32x4 s3 = mfma16(KF[3], qf[mf], zz); \
      f32x4 e0, e1, e2, e3; \
      _Pragma("unroll") \
      for (int j=0;j<4;j++){ \
        e0[j] = EXP2(s0[j]); \
        e1[j] = EXP2(s1[j]); \
        e2[j] = EXP2(s2[j]); \
        e3[j] = EXP2(s3[j]); \
      } \
      lsum4[mf] += (e0+e1)+(e2+e3); \
      s16x8 p0, p1; \
      _Pragma("unroll") \
      for (int j=0;j<4;j++){ \
        p0[j]   = f2bs(e0[j]); \
        p0[4+j] = f2bs(e1[j]); \
        p1[j]   = f2bs(e2[j]); \
        p1[4+j] = f2bs(e3[j]); \
      } \
      o[mf][0] = mfma16(p0, VF[0][0], o[mf][0]); \
      o[mf][0] = mfma16(p1, VF[0][1], o[mf][0]); \
      o[mf][1] = mfma16(p0, VF[1][0], o[mf][1]); \
      o[mf][1] = mfma16(p1, VF[1][1], o[mf][1]); \
    } \
  } while(0)

  s16x8 kfA[4], kfB[4], vfA[2][2], vfB[2][2];
  {
    int w0 = rp[0]; if ((unsigned)w0 > 168u) w0 = 0;
    int w1 = rp[1]; if ((unsigned)w1 > 168u) w1 = 0;
    LOADW(kfA, vfA, w0);
    LOADW(kfB, vfB, w1);
  }
  #pragma unroll 1
  for (int tp=0; tp<5; tp++){
    int wn0 = 0, wn1 = 0;
    if (tp < 4){
      wn0 = rp[2*tp+2]; if ((unsigned)wn0 > 168u) wn0 = 0;
      wn1 = rp[2*tp+3]; if ((unsigned)wn1 > 168u) wn1 = 0;
    }
    COMPW(kfA, vfA);
    if (tp < 4) LOADW(kfA, vfA, wn0);   // latency hides under COMPW(B)
    COMPW(kfB, vfB);
    if (tp < 4) LOADW(kfB, vfB, wn1);   // latency hides under next COMPW(A)
  }
#undef LOADW
#undef COMPW

  // epilogue: lane holds denom partial for query mf*16+l15; outputs are query lh*4+r
  #pragma unroll
  for (int mf=0;mf<4;mf++){
    float tot = (lsum4[mf][0]+lsum4[mf][1]) + (lsum4[mf][2]+lsum4[mf][3]);
    tot += __shfl_xor(tot,16);
    tot += __shfl_xor(tot,32);
    #pragma unroll
    for (int r=0;r<4;r++){
      float inv = 1.f/__shfl(tot, lh*4+r);
      int qr = mf*16 + lh*4 + r;
      int n = (wy*8 + (qr>>3))*HH + wx*8 + (qr&7);
      size_t base = ((size_t)b*NTOK + n)*256 + h*32;
      ao[base +      l15] = (u16)f2bs(o[mf][0][r]*inv + b2f(lepe[base +      l15]));
      ao[base + 16 + l15] = (u16)f2bs(o[mf][1][r]*inv + b2f(lepe[base + 16 + l15]));
    }
  }
}

// ---------------- kernel 7: out = ao @ Wo + bo ----------------
__global__ __launch_bounds__(256) void k_final(const u16* __restrict__ ao,
    const u16* __restrict__ woT, const float* __restrict__ bo, float* __restrict__ out){
  __shared__ __align__(16) short As[128][72];
  __shared__ __align__(16) short Bs[128][72];
  const int m0 = blockIdx.x*128, n0 = blockIdx.y*128;
  const int tid = threadIdx.x, wv = tid>>6, l = tid&63;
  const int wm = (wv>>1)*64, wn = (wv&1)*64;
  const int l15 = l&15, lh = l>>4;
  f32x4 acc[4][4];
  #pragma unroll
  for (int mf=0;mf<4;mf++)
    #pragma unroll
    for (int nf=0;nf<4;nf++) acc[mf][nf] = (f32x4){0.f,0.f,0.f,0.f};

  for (int kk=0; kk<256; kk+=64){
    __syncthreads();
    #pragma unroll
    for (int i=0;i<4;i++){
      int sid = i*256 + tid; int r = sid>>3, cu = (sid&7)*8;
      *(s16x8*)&As[r][cu] = *(const s16x8*)(ao  + (size_t)(m0+r)*256 + kk + cu);
      *(s16x8*)&Bs[r][cu] = *(const s16x8*)(woT + (size_t)(n0+r)*256 + kk + cu);
    }
    __syncthreads();
    #pragma unroll
    for (int ks=0; ks<2; ks++){
      s16x8 af[4], bf[4];
      #pragma unroll
      for (int mf=0; mf<4; mf++) af[mf] = *(const s16x8*)&As[wm+mf*16+l15][ks*32 + lh*8];
      #pragma unroll
      for (int nf=0; nf<4; nf++) bf[nf] = *(const s16x8*)&Bs[wn+nf*16+l15][ks*32 + lh*8];
      #pragma unroll
      for (int mf=0; mf<4; mf++)
        #pragma unroll
        for (int nf=0; nf<4; nf++)
          acc[mf][nf] = mfma16(af[mf], bf[nf], acc[mf][nf]);
    }
  }
  #pragma unroll
  for (int mf=0; mf<4; mf++)
    #pragma unroll
    for (int nf=0; nf<4; nf++){
      int gcol = n0 + wn + nf*16 + l15;
      float bv = bo[gcol];
      #pragma unroll
      for (int r=0;r<4;r++){
        int row = m0 + wm + mf*16 + lh*4 + r;
        out[(size_t)row*256 + gcol] = acc[mf][nf][r] + bv;
      }
    }
}

extern "C" void kernel_launch(void* const* d_in, const int* in_sizes, int n_in,
                              void* d_out, int out_size, void* d_ws, size_t ws_size,
                              hipStream_t stream){
  (void)in_sizes; (void)n_in; (void)out_size;
  if (ws_size < WS_NEEDED) return;
  const float* x    = (const float*)d_in[0];
  const float* Wqkv = (const float*)d_in[1];
  const float* bqkv = (const float*)d_in[2];
  const float* Wo   = (const float*)d_in[3];
  const float* bo   = (const float*)d_in[4];
  const float* lw   = (const float*)d_in[5];
  const float* lb   = (const float*)d_in[6];
  char* ws = (char*)d_ws;
  u16*   wqkvT = (u16*)(ws + OFF_WQKVT);
  u16*   woT   = (u16*)(ws + OFF_WOT);
  float* lwT   = (float*)(ws + OFF_LWT);
  u16*   qbf   = (u16*)(ws + OFF_QBF);
  u16*   kbf   = (u16*)(ws + OFF_KBF);
  u16*   vbf   = (u16*)(ws + OFF_VBF);
  u16*   vwt   = (u16*)(ws + OFF_VWT);
  float* qwin  = (float*)(ws + OFF_QWIN);
  float* kwin  = (float*)(ws + OFF_KWIN);
  int*   ridx  = (int*)(ws + OFF_RIDX);
  u16*   xbf   = (u16*)(ws + OFF_XBF);
  u16*   ao    = (u16*)(ws + OFF_AO);
  u16*   lepe  = (u16*)(ws + OFF_LEPE);
  float* out   = (float*)d_out;

  k_prep   <<<1073, 256, 0, stream>>>(Wqkv, Wo, lw, wqkvT, woT, lwT);
  k_winproj<<<338, 256, 0, stream>>>(x, Wqkv, bqkv, qwin, kwin, xbf);
  k_qkv    <<<dim3(169,6), 256, 0, stream>>>(xbf, wqkvT, bqkv, qbf, kbf, vbf);
  k_vt     <<<1352, 256, 0, stream>>>(vbf, vwt);
  k_router <<<338, 256, 0, stream>>>(qwin, kwin, ridx);
  k_conv   <<<1352, 256, 0, stream>>>(vbf, lwT, lb, lepe);
  k_attn   <<<2704, 64, 0, stream>>>(qbf, kbf, vwt, ridx, lepe, ao);
  k_final  <<<dim3(169,2), 256, 0, stream>>>(ao, woT, bo, out);
}

// Round 17
// 171.976 us; speedup vs baseline: 1.1083x; 1.0644x over previous
//
#include <hip/hip_runtime.h>

using u16   = unsigned short;
using f32x4 = __attribute__((ext_vector_type(4))) float;
using s16x8 = __attribute__((ext_vector_type(8))) short;
using s16x4 = __attribute__((ext_vector_type(4))) short;

#define DEVI static __device__ __forceinline__

DEVI float b2f(u16 u){ union{unsigned int i; float f;} v; v.i = ((unsigned int)u)<<16; return v.f; }
DEVI u16 f2b(float f){ union{float f; unsigned int i;} v; v.f = f;
  unsigned int r = v.i + 0x7fffu + ((v.i>>16)&1u); return (u16)(r>>16); }

// hardware bf16 convert (clang lowers to v_cvt_pk_bf16_f32 on gfx950, RNE)
DEVI short f2bs(float f){
  __bf16 h = (__bf16)f;
  short s;
  __builtin_memcpy(&s, &h, 2);
  return s;
}

// raw v_exp_f32 (no denorm-fixup sequence); inputs here are bounded |x|<~8
#if __has_builtin(__builtin_amdgcn_exp2f)
#define EXP2(x) __builtin_amdgcn_exp2f(x)
#else
#define EXP2(x) __builtin_exp2f(x)
#endif

DEVI f32x4 mfma16(s16x8 a, s16x8 b, f32x4 c){
  return __builtin_amdgcn_mfma_f32_16x16x32_bf16(a, b, c, 0, 0, 0);
}

// async global->LDS: per-lane global src, wave-uniform LDS base (HW adds lane*16)
DEVI void gload16(const void* g, void* l){
  __builtin_amdgcn_global_load_lds(
      (const __attribute__((address_space(1))) void*)g,
      (__attribute__((address_space(3))) void*)l, 16, 0, 0);
}

constexpr int   HH     = 104;
constexpr int   NTOK   = 10816;          // 104*104
constexpr float SLOG2E = 0.0625f * 1.44269504088896340736f;  // SCALE * log2(e)
constexpr float RSCALE = 0.0625f;        // 256^-0.5

// ---- workspace layout (bytes) ----
constexpr size_t OFF_WQKVT = 0x0000000;  // 768*256 bf16
constexpr size_t OFF_WOT   = 0x0060000;  // 256*256 bf16
constexpr size_t OFF_LWT   = 0x0080000;  // 49*256 f32
constexpr size_t OFF_QBF   = 0x0090000;  // 2*10816*256 bf16 (0xA90000)
constexpr size_t OFF_KBF   = 0x0B20000;
constexpr size_t OFF_VBF   = 0x15B0000;
constexpr size_t OFF_VWT   = 0x2040000;  // v window-transposed+kappa-permuted [2][169][256][64] bf16
constexpr size_t OFF_QWIN  = 0x2AD0000;  // f32 [2][169][256]
constexpr size_t OFF_KWIN  = 0x2B25000;
constexpr size_t OFF_RIDX  = 0x2B7A000;  // int [2][169][10]
constexpr size_t OFF_XBF   = 0x2B7E000;  // bf16 x copy (11 MB)
constexpr size_t OFF_AO    = 0x360E000;  // bf16 fused attn+lepe [2][10816][256]
constexpr size_t OFF_LEPE  = 0x409E000;  // bf16 lepe
constexpr size_t WS_NEEDED = 0x55BE000;  // ~86 MB

// ---------------- kernel 0: weight transposes (fp32 -> bf16, lepe_w fp32) ----------------
__global__ void k_prep(const float* __restrict__ Wqkv, const float* __restrict__ Wo,
                       const float* __restrict__ lw,
                       u16* __restrict__ wqkvT, u16* __restrict__ woT, float* __restrict__ lwT){
  int id = blockIdx.x*256 + threadIdx.x;
  if (id < 768*256){
    int n = id >> 8, k = id & 255;
    wqkvT[id] = f2b(Wqkv[k*768 + n]);
  } else if (id < 768*256 + 256*256){
    int o = id - 768*256; int n = o >> 8, k = o & 255;
    woT[o] = f2b(Wo[k*256 + n]);
  } else {
    int o = id - (768*256 + 256*256); int t = o >> 8, c = o & 255;
    lwT[o] = lw[c*49 + t];
  }
}

// ---------------- kernel 1: QKV GEMM (xbf @ Wqkv + b); q pre-scaled by SCALE*log2e ----------------
__global__ __launch_bounds__(256) void k_qkv(const u16* __restrict__ xbf, const u16* __restrict__ wT,
    const float* __restrict__ bias,
    u16* __restrict__ qb, u16* __restrict__ kb, u16* __restrict__ vb){
  __shared__ __align__(16) short As[128][72];
  __shared__ __align__(16) short Bs[128][72];
  const int m0 = blockIdx.x*128, n0 = blockIdx.y*128;
  const int tid = threadIdx.x, wv = tid>>6, l = tid&63;
  const int wm = (wv>>1)*64, wn = (wv&1)*64;
  const int l15 = l&15, lh = l>>4;
  f32x4 acc[4][4];
  #pragma unroll
  for (int mf=0;mf<4;mf++)
    #pragma unroll
    for (int nf=0;nf<4;nf++) acc[mf][nf] = (f32x4){0.f,0.f,0.f,0.f};

  for (int kk=0; kk<256; kk+=64){
    __syncthreads();
    #pragma unroll
    for (int i=0;i<4;i++){
      int sid = i*256 + tid; int r = sid>>3, cu = (sid&7)*8;
      *(s16x8*)&As[r][cu] = *(const s16x8*)(xbf + (size_t)(m0+r)*256 + kk + cu);
      *(s16x8*)&Bs[r][cu] = *(const s16x8*)(wT  + (size_t)(n0+r)*256 + kk + cu);
    }
    __syncthreads();
    #pragma unroll
    for (int ks=0; ks<2; ks++){
      s16x8 af[4], bf[4];
      #pragma unroll
      for (int mf=0; mf<4; mf++) af[mf] = *(const s16x8*)&As[wm+mf*16+l15][ks*32 + lh*8];
      #pragma unroll
      for (int nf=0; nf<4; nf++) bf[nf] = *(const s16x8*)&Bs[wn+nf*16+l15][ks*32 + lh*8];
      #pragma unroll
      for (int mf=0; mf<4; mf++)
        #pragma unroll
        for (int nf=0; nf<4; nf++)
          acc[mf][nf] = mfma16(af[mf], bf[nf], acc[mf][nf]);
    }
  }
  const int sec = n0 >> 8;  // 0:q 1:k 2:v
  u16* dst = sec==0 ? qb : (sec==1 ? kb : vb);
  const float qsc = (sec==0) ? SLOG2E : 1.f;
  #pragma unroll
  for (int mf=0; mf<4; mf++)
    #pragma unroll
    for (int nf=0; nf<4; nf++){
      int gcol = n0 + wn + nf*16 + l15;
      int ccol = gcol & 255;
      float bsv = bias[gcol];
      #pragma unroll
      for (int r=0;r<4;r++){
        int row = m0 + wm + mf*16 + lh*4 + r;
        dst[(size_t)row*256 + ccol] = f2b((acc[mf][nf][r] + bsv)*qsc);
      }
    }
}

// ---------------- kernel 2: fp32 window means of x -> q_win/k_win; also emits bf16 x copy ----
__global__ __launch_bounds__(256) void k_winproj(const float* __restrict__ x,
    const float* __restrict__ Wqkv, const float* __restrict__ bqkv,
    float* __restrict__ qwin, float* __restrict__ kwin, u16* __restrict__ xbf){
  int bp = blockIdx.x; int b = bp/169, p = bp%169;
  int wy = p/13, wx = p%13;
  __shared__ float xm[256];
  int c = threadIdx.x;
  float s = 0.f;
  for (int w=0; w<64; w++){
    int n = (wy*8 + (w>>3))*HH + wx*8 + (w&7);
    size_t off = ((size_t)b*NTOK + n)*256 + c;
    float xv = x[off];
    s += xv;
    xbf[off] = (u16)f2bs(xv);
  }
  xm[c] = s * (1.f/64.f);
  __syncthreads();
  float sq = bqkv[c], sk = bqkv[256 + c];
  #pragma unroll 4
  for (int k=0; k<256; k++){
    float xv = xm[k];
    sq += xv * Wqkv[k*768 + c];
    sk += xv * Wqkv[k*768 + 256 + c];
  }
  qwin[(size_t)bp*256 + c] = sq;
  kwin[(size_t)bp*256 + c] = sk;
}

// ---------------- kernel 3: per-window transpose of v, columns in kappa-permuted key order ----
// slot cw holds V[key]: key = cw5*32 + cw2*16 + cw4*8 + cw3*4 + (cw&3)
__global__ void k_vt(const u16* __restrict__ vb, u16* __restrict__ vwt){
  int blk = blockIdx.x; int bp = blk>>2, ct = blk&3;
  int b = bp/169, p = bp%169;
  int wy = p/13, wx = p%13; int c0 = ct*64;
  __shared__ __align__(16) short L[64][72];
  int tid = threadIdx.x;
  #pragma unroll
  for (int i=0;i<2;i++){
    int sid = i*256 + tid; int r = sid>>3, cu = (sid&7)*8;
    int n = (wy*8 + (r>>3))*HH + wx*8 + (r&7);
    *(s16x8*)&L[r][cu] = *(const s16x8*)(vb + ((size_t)b*NTOK + n)*256 + c0 + cu);
  }
  __syncthreads();
  #pragma unroll
  for (int i=0;i<2;i++){
    int oid = i*256 + tid; int c = oid>>3, wu = (oid&7)*8;
    s16x8 vv;
    #pragma unroll
    for (int j=0;j<8;j++){
      int cw = wu + j;
      int wsrc = ((cw>>5)&1)*32 + ((cw>>2)&1)*16 + ((cw>>4)&1)*8 + ((cw>>3)&1)*4 + (cw&3);
      vv[j] = L[wsrc][c];
    }
    *(s16x8*)(vwt + (size_t)bp*16384 + (size_t)(c0+c)*64 + wu) = vv;
  }
}

// ---------------- kernel 4: router logits + top-10 ----------------
__global__ void k_router(const float* __restrict__ qwin, const float* __restrict__ kwin,
                         int* __restrict__ ridx){
  int bp = blockIdx.x; int b = bp/169;
  __shared__ float qs[256];
  __shared__ float lg[176];
  int tid = threadIdx.x, wv = tid>>6, l = tid&63;
  qs[tid] = qwin[(size_t)bp*256 + tid] * RSCALE;
  __syncthreads();
  const float* kbase = kwin + (size_t)b*169*256;
  for (int q = wv; q < 169; q += 4){
    float s = 0.f;
    #pragma unroll
    for (int j=0;j<4;j++) s += qs[l + 64*j] * kbase[(size_t)q*256 + l + 64*j];
    #pragma unroll
    for (int d=32; d; d>>=1) s += __shfl_xor(s, d);
    if (l == 0) lg[q] = s;
  }
  __syncthreads();
  if (wv == 0){
    for (int t=0;t<10;t++){
      float bv = -1e30f; int bi = 0;
      for (int q=l; q<169; q+=64){
        float v = lg[q];
        if (v > bv || (v == bv && q < bi)){ bv = v; bi = q; }
      }
      #pragma unroll
      for (int d=32; d; d>>=1){
        float ov = __shfl_xor(bv, d); int oi = __shfl_xor(bi, d);
        if (ov > bv || (ov == bv && oi < bi)){ bv = ov; bi = oi; }
      }
      if (l == 0){ ridx[bp*10 + t] = bi; lg[bi] = -1e30f; }
    }
  }
}

// ---------------- kernel 5: LEPE depthwise 7x7, LDS-tiled 8x8x64, bf16 out ----------------
__global__ __launch_bounds__(256) void k_conv(const u16* __restrict__ vb, const float* __restrict__ lwT,
                       const float* __restrict__ lb, u16* __restrict__ lepe){
  __shared__ float Lp[196*64];  // 50176 B
  const int blk = blockIdx.x;
  const int cg = blk & 3; int t = blk >> 2;
  const int tx = t % 13; int t2 = t / 13;
  const int ty = t2 % 13; const int b = t2 / 13;
  const int c0 = cg*64;
  const int tid = threadIdx.x;
  const int lane8 = tid & 7;
  #pragma unroll
  for (int i=0;i<7;i++){
    int sid = i*256 + tid;
    int pp = sid >> 3;
    if (pp < 196){
      int py = pp/14, px = pp - py*14;
      int gy = ty*8 + py - 3, gx = tx*8 + px - 3;
      f32x4 v0 = (f32x4){0.f,0.f,0.f,0.f}, v1 = (f32x4){0.f,0.f,0.f,0.f};
      if ((unsigned)gy < (unsigned)HH && (unsigned)gx < (unsigned)HH){
        s16x8 v = *(const s16x8*)(vb + ((size_t)b*NTOK + gy*HH + gx)*256 + c0 + lane8*8);
        v0[0]=b2f((u16)v[0]); v0[1]=b2f((u16)v[1]); v0[2]=b2f((u16)v[2]); v0[3]=b2f((u16)v[3]);
        v1[0]=b2f((u16)v[4]); v1[1]=b2f((u16)v[5]); v1[2]=b2f((u16)v[6]); v1[3]=b2f((u16)v[7]);
      }
      float* dst = &Lp[pp*64 + lane8*8];
      *(f32x4*)dst = v0;
      *(f32x4*)(dst+4) = v1;
    }
  }
  const int c = tid & 63;
  const int yg = tid >> 6;  // 0..3
  float w[49];
  #pragma unroll
  for (int kt=0; kt<49; kt++) w[kt] = lwT[kt*256 + c0 + c];
  const float bias = lb[c0 + c];
  __syncthreads();
  #pragma unroll
  for (int half=0; half<2; half++){
    const int y = yg + half*4;
    float acc[8];
    #pragma unroll
    for (int xx=0;xx<8;xx++) acc[xx] = bias;
    #pragma unroll
    for (int ky=0;ky<7;ky++){
      const int prow = (y + ky)*14;
      float rv[14];
      #pragma unroll
      for (int xx=0;xx<14;xx++) rv[xx] = Lp[(prow + xx)*64 + c];
      #pragma unroll
      for (int kx=0;kx<7;kx++){
        float wv = w[ky*7+kx];
        #pragma unroll
        for (int xx=0;xx<8;xx++) acc[xx] = fmaf(wv, rv[xx+kx], acc[xx]);
      }
    }
    const int gy = ty*8 + y;
    size_t base = ((size_t)b*NTOK + gy*HH + tx*8)*256 + c0 + c;
    #pragma unroll
    for (int xx=0;xx<8;xx++) lepe[base + (size_t)xx*256] = f2b(acc[xx]);
  }
}

// ---------------- kernel 6: attention, 1 wave/block, LDS parking-buffer prefetch ----------------
// Swapped QK^T (S^T = mfma(K,Q)) -> lane holds 16 P-values for ONE query (keys nf*16+lh*4+r).
// With vwt's kappa permutation those 16 values ARE the lane's two PV A-fragments.
// K/V for window t+1 prefetched via global_load_lds into a 2x8KB LDS double-buffer
// (zero VGPR cost); counted s_waitcnt vmcnt(8) guarantees window t's 8 loads retired.
__global__ __launch_bounds__(64, 3) void k_attn(const u16* __restrict__ qb, const u16* __restrict__ kb,
    const u16* __restrict__ vwt, const int* __restrict__ ridx,
    const u16* __restrict__ lepe, u16* __restrict__ ao){
  __shared__ __align__(16) char Lbuf[2][8192];
  const int blk = blockIdx.x;
  const int h = blk & 7, bp = blk >> 3;
  const int b = bp/169, p = bp%169;
  const int wy = p/13, wx = p%13;
  const int l = threadIdx.x, l15 = l&15, lh = l>>4;
  const int rowoff = (l15>>3)*HH + (l15&7);

  s16x8 qf[4];
  {
    const u16* qbase = qb + ((size_t)b*NTOK + (wy*8)*HH + wx*8 + rowoff)*256 + h*32 + lh*8;
    #pragma unroll
    for (int mf=0;mf<4;mf++) qf[mf] = *(const s16x8*)(qbase + (size_t)mf*2*HH*256);
  }
  f32x4 o[4][2];
  f32x4 lsum4[4];
  #pragma unroll
  for (int mf=0;mf<4;mf++){
    o[mf][0] = (f32x4){0.f,0.f,0.f,0.f};
    o[mf][1] = (f32x4){0.f,0.f,0.f,0.f};
    lsum4[mf] = (f32x4){0.f,0.f,0.f,0.f};
  }

  const int* rp = ridx + bp*10;

  auto issue = [&](int win, int bi){
    int vy = win/13, vx = win - vy*13;
    const u16* kb_ = kb + ((size_t)b*NTOK + (vy*8)*HH + vx*8 + rowoff)*256 + h*32 + lh*8;
    char* Lb = &Lbuf[bi][0];
    gload16(kb_,                    Lb);
    gload16(kb_ + (size_t)2*HH*256, Lb + 1024);
    gload16(kb_ + (size_t)4*HH*256, Lb + 2048);
    gload16(kb_ + (size_t)6*HH*256, Lb + 3072);
    const u16* vb_ = vwt + ((size_t)(b*169 + win)*256 + h*32 + l15)*64 + lh*8;
    gload16(vb_,        Lb + 4096);
    gload16(vb_ + 32,   Lb + 5120);
    gload16(vb_ + 1024, Lb + 6144);
    gload16(vb_ + 1056, Lb + 7168);
  };

  {
    int w0 = rp[0]; if ((unsigned)w0 > 168u) w0 = 0;
    issue(w0, 0);
  }
  int wn = rp[1]; if ((unsigned)wn > 168u) wn = 0;

  #pragma unroll 1
  for (int t=0; t<10; t++){
    const int bi = t & 1;
    if (t < 9){
      issue(wn, bi^1);
      int w2 = (t < 8) ? rp[t+2] : 0; if ((unsigned)w2 > 168u) w2 = 0;
      wn = w2;
      asm volatile("s_waitcnt vmcnt(8)" ::: "memory");
    } else {
      asm volatile("s_waitcnt vmcnt(0)" ::: "memory");
    }
    const char* Lb = &Lbuf[bi][0];
    s16x8 kf[4], vf[2][2];
    #pragma unroll
    for (int nf=0;nf<4;nf++) kf[nf] = *(const s16x8*)(Lb + nf*1024 + l*16);
    vf[0][0] = *(const s16x8*)(Lb + 4096 + l*16);
    vf[0][1] = *(const s16x8*)(Lb + 5120 + l*16);
    vf[1][0] = *(const s16x8*)(Lb + 6144 + l*16);
    vf[1][1] = *(const s16x8*)(Lb + 7168 + l*16);

    #pragma unroll
    for (int mf=0;mf<4;mf++){
      f32x4 zz = (f32x4){0.f,0.f,0.f,0.f};
      f32x4 s0 = mfma16(kf[0], qf[mf], zz);
      f32x4 s1 = mfma16(kf[1], qf[mf], zz);
      f32x4 s2 = mfma16(kf[2], qf[mf], zz);
      f32x4 s3 = mfma16(kf[3], qf[mf], zz);
      f32x4 e0, e1, e2, e3;
      #pragma unroll
      for (int j=0;j<4;j++){
        e0[j] = EXP2(s0[j]);
        e1[j] = EXP2(s1[j]);
        e2[j] = EXP2(s2[j]);
        e3[j] = EXP2(s3[j]);
      }
      lsum4[mf] += (e0+e1)+(e2+e3);
      s16x8 p0, p1;
      #pragma unroll
      for (int j=0;j<4;j++){
        p0[j]   = f2bs(e0[j]);
        p0[4+j] = f2bs(e1[j]);
        p1[j]   = f2bs(e2[j]);
        p1[4+j] = f2bs(e3[j]);
      }
      o[mf][0] = mfma16(p0, vf[0][0], o[mf][0]);
      o[mf][0] = mfma16(p1, vf[0][1], o[mf][0]);
      o[mf][1] = mfma16(p0, vf[1][0], o[mf][1]);
      o[mf][1] = mfma16(p1, vf[1][1], o[mf][1]);
    }
  }

  // epilogue: lane holds denom partial for query mf*16+l15; outputs are query lh*4+r
  #pragma unroll
  for (int mf=0;mf<4;mf++){
    float tot = (lsum4[mf][0]+lsum4[mf][1]) + (lsum4[mf][2]+lsum4[mf][3]);
    tot += __shfl_xor(tot,16);
    tot += __shfl_xor(tot,32);
    #pragma unroll
    for (int r=0;r<4;r++){
      float inv = 1.f/__shfl(tot, lh*4+r);
      int qr = mf*16 + lh*4 + r;
      int n = (wy*8 + (qr>>3))*HH + wx*8 + (qr&7);
      size_t base = ((size_t)b*NTOK + n)*256 + h*32;
      ao[base +      l15] = (u16)f2bs(o[mf][0][r]*inv + b2f(lepe[base +      l15]));
      ao[base + 16 + l15] = (u16)f2bs(o[mf][1][r]*inv + b2f(lepe[base + 16 + l15]));
    }
  }
}

// ---------------- kernel 7: out = ao @ Wo + bo ----------------
__global__ __launch_bounds__(256) void k_final(const u16* __restrict__ ao,
    const u16* __restrict__ woT, const float* __restrict__ bo, float* __restrict__ out){
  __shared__ __align__(16) short As[128][72];
  __shared__ __align__(16) short Bs[128][72];
  const int m0 = blockIdx.x*128, n0 = blockIdx.y*128;
  const int tid = threadIdx.x, wv = tid>>6, l = tid&63;
  const int wm = (wv>>1)*64, wn = (wv&1)*64;
  const int l15 = l&15, lh = l>>4;
  f32x4 acc[4][4];
  #pragma unroll
  for (int mf=0;mf<4;mf++)
    #pragma unroll
    for (int nf=0;nf<4;nf++) acc[mf][nf] = (f32x4){0.f,0.f,0.f,0.f};

  for (int kk=0; kk<256; kk+=64){
    __syncthreads();
    #pragma unroll
    for (int i=0;i<4;i++){
      int sid = i*256 + tid; int r = sid>>3, cu = (sid&7)*8;
      *(s16x8*)&As[r][cu] = *(const s16x8*)(ao  + (size_t)(m0+r)*256 + kk + cu);
      *(s16x8*)&Bs[r][cu] = *(const s16x8*)(woT + (size_t)(n0+r)*256 + kk + cu);
    }
    __syncthreads();
    #pragma unroll
    for (int ks=0; ks<2; ks++){
      s16x8 af[4], bf[4];
      #pragma unroll
      for (int mf=0; mf<4; mf++) af[mf] = *(const s16x8*)&As[wm+mf*16+l15][ks*32 + lh*8];
      #pragma unroll
      for (int nf=0; nf<4; nf++) bf[nf] = *(const s16x8*)&Bs[wn+nf*16+l15][ks*32 + lh*8];
      #pragma unroll
      for (int mf=0; mf<4; mf++)
        #pragma unroll
        for (int nf=0; nf<4; nf++)
          acc[mf][nf] = mfma16(af[mf], bf[nf], acc[mf][nf]);
    }
  }
  #pragma unroll
  for (int mf=0; mf<4; mf++)
    #pragma unroll
    for (int nf=0; nf<4; nf++){
      int gcol = n0 + wn + nf*16 + l15;
      float bv = bo[gcol];
      #pragma unroll
      for (int r=0;r<4;r++){
        int row = m0 + wm + mf*16 + lh*4 + r;
        out[(size_t)row*256 + gcol] = acc[mf][nf][r] + bv;
      }
    }
}

extern "C" void kernel_launch(void* const* d_in, const int* in_sizes, int n_in,
                              void* d_out, int out_size, void* d_ws, size_t ws_size,
                              hipStream_t stream){
  (void)in_sizes; (void)n_in; (void)out_size;
  if (ws_size < WS_NEEDED) return;
  const float* x    = (const float*)d_in[0];
  const float* Wqkv = (const float*)d_in[1];
  const float* bqkv = (const float*)d_in[2];
  const float* Wo   = (const float*)d_in[3];
  const float* bo   = (const float*)d_in[4];
  const float* lw   = (const float*)d_in[5];
  const float* lb   = (const float*)d_in[6];
  char* ws = (char*)d_ws;
  u16*   wqkvT = (u16*)(ws + OFF_WQKVT);
  u16*   woT   = (u16*)(ws + OFF_WOT);
  float* lwT   = (float*)(ws + OFF_LWT);
  u16*   qbf   = (u16*)(ws + OFF_QBF);
  u16*   kbf   = (u16*)(ws + OFF_KBF);
  u16*   vbf   = (u16*)(ws + OFF_VBF);
  u16*   vwt   = (u16*)(ws + OFF_VWT);
  float* qwin  = (float*)(ws + OFF_QWIN);
  float* kwin  = (float*)(ws + OFF_KWIN);
  int*   ridx  = (int*)(ws + OFF_RIDX);
  u16*   xbf   = (u16*)(ws + OFF_XBF);
  u16*   ao    = (u16*)(ws + OFF_AO);
  u16*   lepe  = (u16*)(ws + OFF_LEPE);
  float* out   = (float*)d_out;

  k_prep   <<<1073, 256, 0, stream>>>(Wqkv, Wo, lw, wqkvT, woT, lwT);
  k_winproj<<<338, 256, 0, stream>>>(x, Wqkv, bqkv, qwin, kwin, xbf);
  k_qkv    <<<dim3(169,6), 256, 0, stream>>>(xbf, wqkvT, bqkv, qbf, kbf, vbf);
  k_vt     <<<1352, 256, 0, stream>>>(vbf, vwt);
  k_router <<<338, 256, 0, stream>>>(qwin, kwin, ridx);
  k_conv   <<<1352, 256, 0, stream>>>(vbf, lwT, lb, lepe);
  k_attn   <<<2704, 64, 0, stream>>>(qbf, kbf, vwt, ridx, lepe, ao);
  k_final  <<<dim3(169,2), 256, 0, stream>>>(ao, woT, bo, out);
}

// Round 18
// 170.783 us; speedup vs baseline: 1.1161x; 1.0070x over previous
//
#include <hip/hip_runtime.h>

using u16   = unsigned short;
using f32x4 = __attribute__((ext_vector_type(4))) float;
using s16x8 = __attribute__((ext_vector_type(8))) short;
using s16x4 = __attribute__((ext_vector_type(4))) short;

#define DEVI static __device__ __forceinline__

DEVI float b2f(u16 u){ union{unsigned int i; float f;} v; v.i = ((unsigned int)u)<<16; return v.f; }
DEVI u16 f2b(float f){ union{float f; unsigned int i;} v; v.f = f;
  unsigned int r = v.i + 0x7fffu + ((v.i>>16)&1u); return (u16)(r>>16); }

// hardware bf16 convert (clang lowers to v_cvt_pk_bf16_f32 on gfx950, RNE)
DEVI short f2bs(float f){
  __bf16 h = (__bf16)f;
  short s;
  __builtin_memcpy(&s, &h, 2);
  return s;
}

// raw v_exp_f32 (no denorm-fixup sequence); inputs here are bounded |x|<~8
#if __has_builtin(__builtin_amdgcn_exp2f)
#define EXP2(x) __builtin_amdgcn_exp2f(x)
#else
#define EXP2(x) __builtin_exp2f(x)
#endif

DEVI f32x4 mfma16(s16x8 a, s16x8 b, f32x4 c){
  return __builtin_amdgcn_mfma_f32_16x16x32_bf16(a, b, c, 0, 0, 0);
}

constexpr int   HH     = 104;
constexpr int   NTOK   = 10816;          // 104*104
constexpr float SLOG2E = 0.0625f * 1.44269504088896340736f;  // SCALE * log2(e)
constexpr float RSCALE = 0.0625f;        // 256^-0.5

// ---- workspace layout (bytes) ----
constexpr size_t OFF_WQKVT = 0x0000000;  // 768*256 bf16
constexpr size_t OFF_WOT   = 0x0060000;  // 256*256 bf16
constexpr size_t OFF_LWT   = 0x0080000;  // 49*256 f32
constexpr size_t OFF_QBF   = 0x0090000;  // 2*10816*256 bf16 (0xA90000)
constexpr size_t OFF_KBF   = 0x0B20000;
constexpr size_t OFF_VBF   = 0x15B0000;
constexpr size_t OFF_VWT   = 0x2040000;  // v window-transposed+kappa-permuted [2][169][256][64] bf16
constexpr size_t OFF_QWIN  = 0x2AD0000;  // f32 [2][169][256]
constexpr size_t OFF_KWIN  = 0x2B25000;
constexpr size_t OFF_RIDX  = 0x2B7A000;  // int [2][169][10]
constexpr size_t OFF_XBF   = 0x2B7E000;  // bf16 x copy (11 MB)
constexpr size_t OFF_AO    = 0x360E000;  // bf16 fused attn+lepe [2][10816][256]
constexpr size_t OFF_LEPE  = 0x409E000;  // bf16 lepe
constexpr size_t WS_NEEDED = 0x55BE000;  // ~86 MB

// ---------------- kernel 0: weight transposes (fp32 -> bf16, lepe_w fp32) ----------------
__global__ void k_prep(const float* __restrict__ Wqkv, const float* __restrict__ Wo,
                       const float* __restrict__ lw,
                       u16* __restrict__ wqkvT, u16* __restrict__ woT, float* __restrict__ lwT){
  int id = blockIdx.x*256 + threadIdx.x;
  if (id < 768*256){
    int n = id >> 8, k = id & 255;
    wqkvT[id] = f2b(Wqkv[k*768 + n]);
  } else if (id < 768*256 + 256*256){
    int o = id - 768*256; int n = o >> 8, k = o & 255;
    woT[o] = f2b(Wo[k*256 + n]);
  } else {
    int o = id - (768*256 + 256*256); int t = o >> 8, c = o & 255;
    lwT[o] = lw[c*49 + t];
  }
}

// ---------------- kernel 0b: x fp32 -> bf16 (one-time) ----------------
__global__ void k_xcvt(const float* __restrict__ x, u16* __restrict__ xbf){
  int id = blockIdx.x*256 + threadIdx.x;
  const float* xp = x + (size_t)id*8;
  float4 a0 = *(const float4*)(xp);
  float4 a1 = *(const float4*)(xp + 4);
  s16x8 sv;
  sv[0]=(short)f2b(a0.x); sv[1]=(short)f2b(a0.y); sv[2]=(short)f2b(a0.z); sv[3]=(short)f2b(a0.w);
  sv[4]=(short)f2b(a1.x); sv[5]=(short)f2b(a1.y); sv[6]=(short)f2b(a1.z); sv[7]=(short)f2b(a1.w);
  *(s16x8*)(xbf + (size_t)id*8) = sv;
}

// ---------------- kernel 1: QKV GEMM (xbf @ Wqkv + b); q pre-scaled by SCALE*log2e ----------------
__global__ __launch_bounds__(256) void k_qkv(const u16* __restrict__ xbf, const u16* __restrict__ wT,
    const float* __restrict__ bias,
    u16* __restrict__ qb, u16* __restrict__ kb, u16* __restrict__ vb){
  __shared__ __align__(16) short As[128][72];
  __shared__ __align__(16) short Bs[128][72];
  const int m0 = blockIdx.x*128, n0 = blockIdx.y*128;
  const int tid = threadIdx.x, wv = tid>>6, l = tid&63;
  const int wm = (wv>>1)*64, wn = (wv&1)*64;
  const int l15 = l&15, lh = l>>4;
  f32x4 acc[4][4];
  #pragma unroll
  for (int mf=0;mf<4;mf++)
    #pragma unroll
    for (int nf=0;nf<4;nf++) acc[mf][nf] = (f32x4){0.f,0.f,0.f,0.f};

  for (int kk=0; kk<256; kk+=64){
    __syncthreads();
    #pragma unroll
    for (int i=0;i<4;i++){
      int sid = i*256 + tid; int r = sid>>3, cu = (sid&7)*8;
      *(s16x8*)&As[r][cu] = *(const s16x8*)(xbf + (size_t)(m0+r)*256 + kk + cu);
      *(s16x8*)&Bs[r][cu] = *(const s16x8*)(wT  + (size_t)(n0+r)*256 + kk + cu);
    }
    __syncthreads();
    #pragma unroll
    for (int ks=0; ks<2; ks++){
      s16x8 af[4], bf[4];
      #pragma unroll
      for (int mf=0; mf<4; mf++) af[mf] = *(const s16x8*)&As[wm+mf*16+l15][ks*32 + lh*8];
      #pragma unroll
      for (int nf=0; nf<4; nf++) bf[nf] = *(const s16x8*)&Bs[wn+nf*16+l15][ks*32 + lh*8];
      #pragma unroll
      for (int mf=0; mf<4; mf++)
        #pragma unroll
        for (int nf=0; nf<4; nf++)
          acc[mf][nf] = mfma16(af[mf], bf[nf], acc[mf][nf]);
    }
  }
  const int sec = n0 >> 8;  // 0:q 1:k 2:v
  u16* dst = sec==0 ? qb : (sec==1 ? kb : vb);
  const float qsc = (sec==0) ? SLOG2E : 1.f;
  #pragma unroll
  for (int mf=0; mf<4; mf++)
    #pragma unroll
    for (int nf=0; nf<4; nf++){
      int gcol = n0 + wn + nf*16 + l15;
      int ccol = gcol & 255;
      float bsv = bias[gcol];
      #pragma unroll
      for (int r=0;r<4;r++){
        int row = m0 + wm + mf*16 + lh*4 + r;
        dst[(size_t)row*256 + ccol] = f2b((acc[mf][nf][r] + bsv)*qsc);
      }
    }
}

// ---------------- kernel 2: fp32 window means of x, projected -> q_win/k_win ----------------
__global__ __launch_bounds__(256) void k_winproj(const float* __restrict__ x,
    const float* __restrict__ Wqkv, const float* __restrict__ bqkv,
    float* __restrict__ qwin, float* __restrict__ kwin){
  int bp = blockIdx.x; int b = bp/169, p = bp%169;
  int wy = p/13, wx = p%13;
  __shared__ float xm[256];
  int c = threadIdx.x;
  float s = 0.f;
  for (int w=0; w<64; w++){
    int n = (wy*8 + (w>>3))*HH + wx*8 + (w&7);
    s += x[((size_t)b*NTOK + n)*256 + c];
  }
  xm[c] = s * (1.f/64.f);
  __syncthreads();
  float sq = bqkv[c], sk = bqkv[256 + c];
  #pragma unroll 4
  for (int k=0; k<256; k++){
    float xv = xm[k];
    sq += xv * Wqkv[k*768 + c];
    sk += xv * Wqkv[k*768 + 256 + c];
  }
  qwin[(size_t)bp*256 + c] = sq;
  kwin[(size_t)bp*256 + c] = sk;
}

// ---------------- kernel 3: per-window transpose of v, columns in kappa-permuted key order ----
// slot cw holds V[key]: key = cw5*32 + cw2*16 + cw4*8 + cw3*4 + (cw&3)
__global__ void k_vt(const u16* __restrict__ vb, u16* __restrict__ vwt){
  int blk = blockIdx.x; int bp = blk>>2, ct = blk&3;
  int b = bp/169, p = bp%169;
  int wy = p/13, wx = p%13; int c0 = ct*64;
  __shared__ __align__(16) short L[64][72];
  int tid = threadIdx.x;
  #pragma unroll
  for (int i=0;i<2;i++){
    int sid = i*256 + tid; int r = sid>>3, cu = (sid&7)*8;
    int n = (wy*8 + (r>>3))*HH + wx*8 + (r&7);
    *(s16x8*)&L[r][cu] = *(const s16x8*)(vb + ((size_t)b*NTOK + n)*256 + c0 + cu);
  }
  __syncthreads();
  #pragma unroll
  for (int i=0;i<2;i++){
    int oid = i*256 + tid; int c = oid>>3, wu = (oid&7)*8;
    s16x8 vv;
    #pragma unroll
    for (int j=0;j<8;j++){
      int cw = wu + j;
      int wsrc = ((cw>>5)&1)*32 + ((cw>>2)&1)*16 + ((cw>>4)&1)*8 + ((cw>>3)&1)*4 + (cw&3);
      vv[j] = L[wsrc][c];
    }
    *(s16x8*)(vwt + (size_t)bp*16384 + (size_t)(c0+c)*64 + wu) = vv;
  }
}

// ---------------- kernel 4: router logits + top-10 ----------------
__global__ void k_router(const float* __restrict__ qwin, const float* __restrict__ kwin,
                         int* __restrict__ ridx){
  int bp = blockIdx.x; int b = bp/169;
  __shared__ float qs[256];
  __shared__ float lg[176];
  int tid = threadIdx.x, wv = tid>>6, l = tid&63;
  qs[tid] = qwin[(size_t)bp*256 + tid] * RSCALE;
  __syncthreads();
  const float* kbase = kwin + (size_t)b*169*256;
  for (int q = wv; q < 169; q += 4){
    float s = 0.f;
    #pragma unroll
    for (int j=0;j<4;j++) s += qs[l + 64*j] * kbase[(size_t)q*256 + l + 64*j];
    #pragma unroll
    for (int d=32; d; d>>=1) s += __shfl_xor(s, d);
    if (l == 0) lg[q] = s;
  }
  __syncthreads();
  if (wv == 0){
    for (int t=0;t<10;t++){
      float bv = -1e30f; int bi = 0;
      for (int q=l; q<169; q+=64){
        float v = lg[q];
        if (v > bv || (v == bv && q < bi)){ bv = v; bi = q; }
      }
      #pragma unroll
      for (int d=32; d; d>>=1){
        float ov = __shfl_xor(bv, d); int oi = __shfl_xor(bi, d);
        if (ov > bv || (ov == bv && oi < bi)){ bv = ov; bi = oi; }
      }
      if (l == 0){ ridx[bp*10 + t] = bi; lg[bi] = -1e30f; }
    }
  }
}

// ---------------- kernel 5: LEPE depthwise 7x7, LDS-tiled 8x8x64, bf16 out ----------------
__global__ __launch_bounds__(256) void k_conv(const u16* __restrict__ vb, const float* __restrict__ lwT,
                       const float* __restrict__ lb, u16* __restrict__ lepe){
  __shared__ float Lp[196*64];  // 50176 B
  const int blk = blockIdx.x;
  const int cg = blk & 3; int t = blk >> 2;
  const int tx = t % 13; int t2 = t / 13;
  const int ty = t2 % 13; const int b = t2 / 13;
  const int c0 = cg*64;
  const int tid = threadIdx.x;
  const int lane8 = tid & 7;
  #pragma unroll
  for (int i=0;i<7;i++){
    int sid = i*256 + tid;
    int pp = sid >> 3;
    if (pp < 196){
      int py = pp/14, px = pp - py*14;
      int gy = ty*8 + py - 3, gx = tx*8 + px - 3;
      f32x4 v0 = (f32x4){0.f,0.f,0.f,0.f}, v1 = (f32x4){0.f,0.f,0.f,0.f};
      if ((unsigned)gy < (unsigned)HH && (unsigned)gx < (unsigned)HH){
        s16x8 v = *(const s16x8*)(vb + ((size_t)b*NTOK + gy*HH + gx)*256 + c0 + lane8*8);
        v0[0]=b2f((u16)v[0]); v0[1]=b2f((u16)v[1]); v0[2]=b2f((u16)v[2]); v0[3]=b2f((u16)v[3]);
        v1[0]=b2f((u16)v[4]); v1[1]=b2f((u16)v[5]); v1[2]=b2f((u16)v[6]); v1[3]=b2f((u16)v[7]);
      }
      float* dst = &Lp[pp*64 + lane8*8];
      *(f32x4*)dst = v0;
      *(f32x4*)(dst+4) = v1;
    }
  }
  const int c = tid & 63;
  const int yg = tid >> 6;  // 0..3
  float w[49];
  #pragma unroll
  for (int kt=0; kt<49; kt++) w[kt] = lwT[kt*256 + c0 + c];
  const float bias = lb[c0 + c];
  __syncthreads();
  #pragma unroll
  for (int half=0; half<2; half++){
    const int y = yg + half*4;
    float acc[8];
    #pragma unroll
    for (int xx=0;xx<8;xx++) acc[xx] = bias;
    #pragma unroll
    for (int ky=0;ky<7;ky++){
      const int prow = (y + ky)*14;
      float rv[14];
      #pragma unroll
      for (int xx=0;xx<14;xx++) rv[xx] = Lp[(prow + xx)*64 + c];
      #pragma unroll
      for (int kx=0;kx<7;kx++){
        float wv = w[ky*7+kx];
        #pragma unroll
        for (int xx=0;xx<8;xx++) acc[xx] = fmaf(wv, rv[xx+kx], acc[xx]);
      }
    }
    const int gy = ty*8 + y;
    size_t base = ((size_t)b*NTOK + gy*HH + tx*8)*256 + c0 + c;
    #pragma unroll
    for (int xx=0;xx<8;xx++) lepe[base + (size_t)xx*256] = f2b(acc[xx]);
  }
}

// ---------------- kernel 6: attention, 1 wave/block, ZERO LDS, raw v_exp_f32 ----------------
// Swapped QK^T (S^T = mfma(K,Q)) -> lane holds 16 P-values for ONE query (keys nf*16+lh*4+r).
// With vwt's kappa permutation those 16 values ARE the lane's two PV A-fragments.
__global__ __launch_bounds__(64, 3) void k_attn(const u16* __restrict__ qb, const u16* __restrict__ kb,
    const u16* __restrict__ vwt, const int* __restrict__ ridx,
    const u16* __restrict__ lepe, u16* __restrict__ ao){
  const int blk = blockIdx.x;
  const int h = blk & 7, bp = blk >> 3;
  const int b = bp/169, p = bp%169;
  const int wy = p/13, wx = p%13;
  const int l = threadIdx.x, l15 = l&15, lh = l>>4;
  const int rowoff = (l15>>3)*HH + (l15&7);

  s16x8 qf[4];
  {
    const u16* qbase = qb + ((size_t)b*NTOK + (wy*8)*HH + wx*8 + rowoff)*256 + h*32 + lh*8;
    #pragma unroll
    for (int mf=0;mf<4;mf++) qf[mf] = *(const s16x8*)(qbase + (size_t)mf*2*HH*256);
  }
  f32x4 o[4][2];
  f32x4 lsum4[4];
  #pragma unroll
  for (int mf=0;mf<4;mf++){
    o[mf][0] = (f32x4){0.f,0.f,0.f,0.f};
    o[mf][1] = (f32x4){0.f,0.f,0.f,0.f};
    lsum4[mf] = (f32x4){0.f,0.f,0.f,0.f};
  }

  const int* rp = ridx + bp*10;
  int win = rp[0];
  for (int t=0;t<10;t++){
    int wnext = (t<9) ? rp[t+1] : 0;     // prefetch next window index (off-chain)
    if ((unsigned)win > 168u) win = 0;
    int vy = win/13, vx = win - vy*13;
    const u16* kbase = kb + ((size_t)b*NTOK + (vy*8)*HH + vx*8 + rowoff)*256 + h*32 + lh*8;
    s16x8 kf[4];
    #pragma unroll
    for (int nf=0;nf<4;nf++) kf[nf] = *(const s16x8*)(kbase + (size_t)nf*2*HH*256);
    const u16* vbase = vwt + ((size_t)(b*169 + win)*256 + h*32 + l15)*64 + lh*8;
    s16x8 vf[2][2];
    #pragma unroll
    for (int d=0;d<2;d++)
      #pragma unroll
      for (int ks=0;ks<2;ks++)
        vf[d][ks] = *(const s16x8*)(vbase + d*1024 + ks*32);

    #pragma unroll
    for (int mf=0;mf<4;mf++){
      f32x4 s0 = mfma16(kf[0], qf[mf], (f32x4){0.f,0.f,0.f,0.f});
      f32x4 s1 = mfma16(kf[1], qf[mf], (f32x4){0.f,0.f,0.f,0.f});
      f32x4 s2 = mfma16(kf[2], qf[mf], (f32x4){0.f,0.f,0.f,0.f});
      f32x4 s3 = mfma16(kf[3], qf[mf], (f32x4){0.f,0.f,0.f,0.f});
      f32x4 e0, e1, e2, e3;
      #pragma unroll
      for (int j=0;j<4;j++){
        e0[j] = EXP2(s0[j]);
        e1[j] = EXP2(s1[j]);
        e2[j] = EXP2(s2[j]);
        e3[j] = EXP2(s3[j]);
      }
      lsum4[mf] += (e0+e1)+(e2+e3);
      // pack P into the two A-fragments via HW cvt (compiler emits v_cvt_pk_bf16_f32)
      s16x8 p0, p1;
      #pragma unroll
      for (int j=0;j<4;j++){
        p0[j]   = f2bs(e0[j]);
        p0[4+j] = f2bs(e1[j]);
        p1[j]   = f2bs(e2[j]);
        p1[4+j] = f2bs(e3[j]);
      }
      o[mf][0] = mfma16(p0, vf[0][0], o[mf][0]);
      o[mf][0] = mfma16(p1, vf[0][1], o[mf][0]);
      o[mf][1] = mfma16(p0, vf[1][0], o[mf][1]);
      o[mf][1] = mfma16(p1, vf[1][1], o[mf][1]);
    }
    win = wnext;
  }
  // epilogue: lane holds denom partial for query mf*16+l15; outputs are query lh*4+r
  #pragma unroll
  for (int mf=0;mf<4;mf++){
    float tot = (lsum4[mf][0]+lsum4[mf][1]) + (lsum4[mf][2]+lsum4[mf][3]);
    tot += __shfl_xor(tot,16);
    tot += __shfl_xor(tot,32);
    #pragma unroll
    for (int r=0;r<4;r++){
      float inv = 1.f/__shfl(tot, lh*4+r);
      int qr = mf*16 + lh*4 + r;
      int n = (wy*8 + (qr>>3))*HH + wx*8 + (qr&7);
      size_t base = ((size_t)b*NTOK + n)*256 + h*32;
      ao[base +      l15] = (u16)f2bs(o[mf][0][r]*inv + b2f(lepe[base +      l15]));
      ao[base + 16 + l15] = (u16)f2bs(o[mf][1][r]*inv + b2f(lepe[base + 16 + l15]));
    }
  }
}

// ---------------- kernel 7: out = ao @ Wo + bo ----------------
__global__ __launch_bounds__(256) void k_final(const u16* __restrict__ ao,
    const u16* __restrict__ woT, const float* __restrict__ bo, float* __restrict__ out){
  __shared__ __align__(16) short As[128][72];
  __shared__ __align__(16) short Bs[128][72];
  const int m0 = blockIdx.x*128, n0 = blockIdx.y*128;
  const int tid = threadIdx.x, wv = tid>>6, l = tid&63;
  const int wm = (wv>>1)*64, wn = (wv&1)*64;
  const int l15 = l&15, lh = l>>4;
  f32x4 acc[4][4];
  #pragma unroll
  for (int mf=0;mf<4;mf++)
    #pragma unroll
    for (int nf=0;nf<4;nf++) acc[mf][nf] = (f32x4){0.f,0.f,0.f,0.f};

  for (int kk=0; kk<256; kk+=64){
    __syncthreads();
    #pragma unroll
    for (int i=0;i<4;i++){
      int sid = i*256 + tid; int r = sid>>3, cu = (sid&7)*8;
      *(s16x8*)&As[r][cu] = *(const s16x8*)(ao  + (size_t)(m0+r)*256 + kk + cu);
      *(s16x8*)&Bs[r][cu] = *(const s16x8*)(woT + (size_t)(n0+r)*256 + kk + cu);
    }
    __syncthreads();
    #pragma unroll
    for (int ks=0; ks<2; ks++){
      s16x8 af[4], bf[4];
      #pragma unroll
      for (int mf=0; mf<4; mf++) af[mf] = *(const s16x8*)&As[wm+mf*16+l15][ks*32 + lh*8];
      #pragma unroll
      for (int nf=0; nf<4; nf++) bf[nf] = *(const s16x8*)&Bs[wn+nf*16+l15][ks*32 + lh*8];
      #pragma unroll
      for (int mf=0; mf<4; mf++)
        #pragma unroll
        for (int nf=0; nf<4; nf++)
          acc[mf][nf] = mfma16(af[mf], bf[nf], acc[mf][nf]);
    }
  }
  #pragma unroll
  for (int mf=0; mf<4; mf++)
    #pragma unroll
    for (int nf=0; nf<4; nf++){
      int gcol = n0 + wn + nf*16 + l15;
      float bv = bo[gcol];
      #pragma unroll
      for (int r=0;r<4;r++){
        int row = m0 + wm + mf*16 + lh*4 + r;
        out[(size_t)row*256 + gcol] = acc[mf][nf][r] + bv;
      }
    }
}

extern "C" void kernel_launch(void* const* d_in, const int* in_sizes, int n_in,
                              void* d_out, int out_size, void* d_ws, size_t ws_size,
                              hipStream_t stream){
  (void)in_sizes; (void)n_in; (void)out_size;
  if (ws_size < WS_NEEDED) return;
  const float* x    = (const float*)d_in[0];
  const float* Wqkv = (const float*)d_in[1];
  const float* bqkv = (const float*)d_in[2];
  const float* Wo   = (const float*)d_in[3];
  const float* bo   = (const float*)d_in[4];
  const float* lw   = (const float*)d_in[5];
  const float* lb   = (const float*)d_in[6];
  char* ws = (char*)d_ws;
  u16*   wqkvT = (u16*)(ws + OFF_WQKVT);
  u16*   woT   = (u16*)(ws + OFF_WOT);
  float* lwT   = (float*)(ws + OFF_LWT);
  u16*   qbf   = (u16*)(ws + OFF_QBF);
  u16*   kbf   = (u16*)(ws + OFF_KBF);
  u16*   vbf   = (u16*)(ws + OFF_VBF);
  u16*   vwt   = (u16*)(ws + OFF_VWT);
  float* qwin  = (float*)(ws + OFF_QWIN);
  float* kwin  = (float*)(ws + OFF_KWIN);
  int*   ridx  = (int*)(ws + OFF_RIDX);
  u16*   xbf   = (u16*)(ws + OFF_XBF);
  u16*   ao    = (u16*)(ws + OFF_AO);
  u16*   lepe  = (u16*)(ws + OFF_LEPE);
  float* out   = (float*)d_out;

  k_prep   <<<1073, 256, 0, stream>>>(Wqkv, Wo, lw, wqkvT, woT, lwT);
  k_xcvt   <<<2704, 256, 0, stream>>>(x, xbf);
  k_qkv    <<<dim3(169,6), 256, 0, stream>>>(xbf, wqkvT, bqkv, qbf, kbf, vbf);
  k_winproj<<<338, 256, 0, stream>>>(x, Wqkv, bqkv, qwin, kwin);
  k_vt     <<<1352, 256, 0, stream>>>(vbf, vwt);
  k_router <<<338, 256, 0, stream>>>(qwin, kwin, ridx);
  k_conv   <<<1352, 256, 0, stream>>>(vbf, lwT, lb, lepe);
  k_attn   <<<2704, 64, 0, stream>>>(qbf, kbf, vwt, ridx, lepe, ao);
  k_final  <<<dim3(169,2), 256, 0, stream>>>(ao, woT, bo, out);
}

// Round 19
// 166.538 us; speedup vs baseline: 1.1445x; 1.0255x over previous
//
#include <hip/hip_runtime.h>

using u16   = unsigned short;
using f32x4 = __attribute__((ext_vector_type(4))) float;
using s16x8 = __attribute__((ext_vector_type(8))) short;
using s16x4 = __attribute__((ext_vector_type(4))) short;

#define DEVI static __device__ __forceinline__

DEVI float b2f(u16 u){ union{unsigned int i; float f;} v; v.i = ((unsigned int)u)<<16; return v.f; }
DEVI u16 f2b(float f){ union{float f; unsigned int i;} v; v.f = f;
  unsigned int r = v.i + 0x7fffu + ((v.i>>16)&1u); return (u16)(r>>16); }

// hardware bf16 convert (clang lowers to v_cvt_pk_bf16_f32 on gfx950, RNE)
DEVI short f2bs(float f){
  __bf16 h = (__bf16)f;
  short s;
  __builtin_memcpy(&s, &h, 2);
  return s;
}

// raw v_exp_f32 (no denorm-fixup sequence); inputs here are bounded |x|<~8
#if __has_builtin(__builtin_amdgcn_exp2f)
#define EXP2(x) __builtin_amdgcn_exp2f(x)
#else
#define EXP2(x) __builtin_exp2f(x)
#endif

DEVI f32x4 mfma16(s16x8 a, s16x8 b, f32x4 c){
  return __builtin_amdgcn_mfma_f32_16x16x32_bf16(a, b, c, 0, 0, 0);
}

constexpr int   HH     = 104;
constexpr int   NTOK   = 10816;          // 104*104
constexpr float SLOG2E = 0.0625f * 1.44269504088896340736f;  // SCALE * log2(e)
constexpr float RSCALE = 0.0625f;        // 256^-0.5

// ---- workspace layout (bytes) ----
constexpr size_t OFF_WQKVT = 0x0000000;  // 768*256 bf16
constexpr size_t OFF_WOT   = 0x0060000;  // 256*256 bf16
constexpr size_t OFF_LWT   = 0x0080000;  // 49*256 f32
constexpr size_t OFF_QBF   = 0x0090000;  // 2*10816*256 bf16 (0xA90000)
constexpr size_t OFF_KBF   = 0x0B20000;
constexpr size_t OFF_VBF   = 0x15B0000;
constexpr size_t OFF_VWT   = 0x2040000;  // v window-transposed+kappa-permuted [2][169][256][64] bf16
constexpr size_t OFF_QWIN  = 0x2AD0000;  // f32 [2][169][256]
constexpr size_t OFF_KWIN  = 0x2B25000;
constexpr size_t OFF_RIDX  = 0x2B7A000;  // int [2][169][10]
constexpr size_t OFF_XBF   = 0x2B7E000;  // bf16 x copy (11 MB)
constexpr size_t OFF_AO    = 0x360E000;  // bf16 fused attn+lepe [2][10816][256]
constexpr size_t OFF_LEPE  = 0x409E000;  // bf16 lepe
constexpr size_t WS_NEEDED = 0x55BE000;  // ~86 MB

// ---------------- kernel 0: weight transposes (fp32 -> bf16, lepe_w fp32) ----------------
__global__ void k_prep(const float* __restrict__ Wqkv, const float* __restrict__ Wo,
                       const float* __restrict__ lw,
                       u16* __restrict__ wqkvT, u16* __restrict__ woT, float* __restrict__ lwT){
  int id = blockIdx.x*256 + threadIdx.x;
  if (id < 768*256){
    int n = id >> 8, k = id & 255;
    wqkvT[id] = f2b(Wqkv[k*768 + n]);
  } else if (id < 768*256 + 256*256){
    int o = id - 768*256; int n = o >> 8, k = o & 255;
    woT[o] = f2b(Wo[k*256 + n]);
  } else {
    int o = id - (768*256 + 256*256); int t = o >> 8, c = o & 255;
    lwT[o] = lw[c*49 + t];
  }
}

// ---------------- kernel 1: QKV GEMM (xbf @ Wqkv + b); q pre-scaled by SCALE*log2e ----------------
__global__ __launch_bounds__(256) void k_qkv(const u16* __restrict__ xbf, const u16* __restrict__ wT,
    const float* __restrict__ bias,
    u16* __restrict__ qb, u16* __restrict__ kb, u16* __restrict__ vb){
  __shared__ __align__(16) short As[128][72];
  __shared__ __align__(16) short Bs[128][72];
  const int m0 = blockIdx.x*128, n0 = blockIdx.y*128;
  const int tid = threadIdx.x, wv = tid>>6, l = tid&63;
  const int wm = (wv>>1)*64, wn = (wv&1)*64;
  const int l15 = l&15, lh = l>>4;
  f32x4 acc[4][4];
  #pragma unroll
  for (int mf=0;mf<4;mf++)
    #pragma unroll
    for (int nf=0;nf<4;nf++) acc[mf][nf] = (f32x4){0.f,0.f,0.f,0.f};

  for (int kk=0; kk<256; kk+=64){
    __syncthreads();
    #pragma unroll
    for (int i=0;i<4;i++){
      int sid = i*256 + tid; int r = sid>>3, cu = (sid&7)*8;
      *(s16x8*)&As[r][cu] = *(const s16x8*)(xbf + (size_t)(m0+r)*256 + kk + cu);
      *(s16x8*)&Bs[r][cu] = *(const s16x8*)(wT  + (size_t)(n0+r)*256 + kk + cu);
    }
    __syncthreads();
    #pragma unroll
    for (int ks=0; ks<2; ks++){
      s16x8 af[4], bf[4];
      #pragma unroll
      for (int mf=0; mf<4; mf++) af[mf] = *(const s16x8*)&As[wm+mf*16+l15][ks*32 + lh*8];
      #pragma unroll
      for (int nf=0; nf<4; nf++) bf[nf] = *(const s16x8*)&Bs[wn+nf*16+l15][ks*32 + lh*8];
      #pragma unroll
      for (int mf=0; mf<4; mf++)
        #pragma unroll
        for (int nf=0; nf<4; nf++)
          acc[mf][nf] = mfma16(af[mf], bf[nf], acc[mf][nf]);
    }
  }
  const int sec = n0 >> 8;  // 0:q 1:k 2:v
  u16* dst = sec==0 ? qb : (sec==1 ? kb : vb);
  const float qsc = (sec==0) ? SLOG2E : 1.f;
  #pragma unroll
  for (int mf=0; mf<4; mf++)
    #pragma unroll
    for (int nf=0; nf<4; nf++){
      int gcol = n0 + wn + nf*16 + l15;
      int ccol = gcol & 255;
      float bsv = bias[gcol];
      #pragma unroll
      for (int r=0;r<4;r++){
        int row = m0 + wm + mf*16 + lh*4 + r;
        dst[(size_t)row*256 + ccol] = f2b((acc[mf][nf][r] + bsv)*qsc);
      }
    }
}

// ---------------- kernel 2: fp32 window means of x -> q_win/k_win; also emits bf16 x copy ----
__global__ __launch_bounds__(256) void k_winproj(const float* __restrict__ x,
    const float* __restrict__ Wqkv, const float* __restrict__ bqkv,
    float* __restrict__ qwin, float* __restrict__ kwin, u16* __restrict__ xbf){
  int bp = blockIdx.x; int b = bp/169, p = bp%169;
  int wy = p/13, wx = p%13;
  __shared__ float xm[256];
  int c = threadIdx.x;
  float s = 0.f;
  for (int w=0; w<64; w++){
    int n = (wy*8 + (w>>3))*HH + wx*8 + (w&7);
    size_t off = ((size_t)b*NTOK + n)*256 + c;
    float xv = x[off];
    s += xv;
    xbf[off] = (u16)f2bs(xv);
  }
  xm[c] = s * (1.f/64.f);
  __syncthreads();
  float sq = bqkv[c], sk = bqkv[256 + c];
  #pragma unroll 4
  for (int k=0; k<256; k++){
    float xv = xm[k];
    sq += xv * Wqkv[k*768 + c];
    sk += xv * Wqkv[k*768 + 256 + c];
  }
  qwin[(size_t)bp*256 + c] = sq;
  kwin[(size_t)bp*256 + c] = sk;
}

// ---------------- kernel 3: per-window transpose of v, columns in kappa-permuted key order ----
// slot cw holds V[key]: key = cw5*32 + cw2*16 + cw4*8 + cw3*4 + (cw&3)
__global__ void k_vt(const u16* __restrict__ vb, u16* __restrict__ vwt){
  int blk = blockIdx.x; int bp = blk>>2, ct = blk&3;
  int b = bp/169, p = bp%169;
  int wy = p/13, wx = p%13; int c0 = ct*64;
  __shared__ __align__(16) short L[64][72];
  int tid = threadIdx.x;
  #pragma unroll
  for (int i=0;i<2;i++){
    int sid = i*256 + tid; int r = sid>>3, cu = (sid&7)*8;
    int n = (wy*8 + (r>>3))*HH + wx*8 + (r&7);
    *(s16x8*)&L[r][cu] = *(const s16x8*)(vb + ((size_t)b*NTOK + n)*256 + c0 + cu);
  }
  __syncthreads();
  #pragma unroll
  for (int i=0;i<2;i++){
    int oid = i*256 + tid; int c = oid>>3, wu = (oid&7)*8;
    s16x8 vv;
    #pragma unroll
    for (int j=0;j<8;j++){
      int cw = wu + j;
      int wsrc = ((cw>>5)&1)*32 + ((cw>>2)&1)*16 + ((cw>>4)&1)*8 + ((cw>>3)&1)*4 + (cw&3);
      vv[j] = L[wsrc][c];
    }
    *(s16x8*)(vwt + (size_t)bp*16384 + (size_t)(c0+c)*64 + wu) = vv;
  }
}

// ---------------- kernel 4: router logits + top-10 ----------------
__global__ void k_router(const float* __restrict__ qwin, const float* __restrict__ kwin,
                         int* __restrict__ ridx){
  int bp = blockIdx.x; int b = bp/169;
  __shared__ float qs[256];
  __shared__ float lg[176];
  int tid = threadIdx.x, wv = tid>>6, l = tid&63;
  qs[tid] = qwin[(size_t)bp*256 + tid] * RSCALE;
  __syncthreads();
  const float* kbase = kwin + (size_t)b*169*256;
  for (int q = wv; q < 169; q += 4){
    float s = 0.f;
    #pragma unroll
    for (int j=0;j<4;j++) s += qs[l + 64*j] * kbase[(size_t)q*256 + l + 64*j];
    #pragma unroll
    for (int d=32; d; d>>=1) s += __shfl_xor(s, d);
    if (l == 0) lg[q] = s;
  }
  __syncthreads();
  if (wv == 0){
    for (int t=0;t<10;t++){
      float bv = -1e30f; int bi = 0;
      for (int q=l; q<169; q+=64){
        float v = lg[q];
        if (v > bv || (v == bv && q < bi)){ bv = v; bi = q; }
      }
      #pragma unroll
      for (int d=32; d; d>>=1){
        float ov = __shfl_xor(bv, d); int oi = __shfl_xor(bi, d);
        if (ov > bv || (ov == bv && oi < bi)){ bv = ov; bi = oi; }
      }
      if (l == 0){ ridx[bp*10 + t] = bi; lg[bi] = -1e30f; }
    }
  }
}

// ---------------- kernel 5: LEPE depthwise 7x7, LDS-tiled 8x8x64, bf16 out ----------------
__global__ __launch_bounds__(256) void k_conv(const u16* __restrict__ vb, const float* __restrict__ lwT,
                       const float* __restrict__ lb, u16* __restrict__ lepe){
  __shared__ float Lp[196*64];  // 50176 B
  const int blk = blockIdx.x;
  const int cg = blk & 3; int t = blk >> 2;
  const int tx = t % 13; int t2 = t / 13;
  const int ty = t2 % 13; const int b = t2 / 13;
  const int c0 = cg*64;
  const int tid = threadIdx.x;
  const int lane8 = tid & 7;
  #pragma unroll
  for (int i=0;i<7;i++){
    int sid = i*256 + tid;
    int pp = sid >> 3;
    if (pp < 196){
      int py = pp/14, px = pp - py*14;
      int gy = ty*8 + py - 3, gx = tx*8 + px - 3;
      f32x4 v0 = (f32x4){0.f,0.f,0.f,0.f}, v1 = (f32x4){0.f,0.f,0.f,0.f};
      if ((unsigned)gy < (unsigned)HH && (unsigned)gx < (unsigned)HH){
        s16x8 v = *(const s16x8*)(vb + ((size_t)b*NTOK + gy*HH + gx)*256 + c0 + lane8*8);
        v0[0]=b2f((u16)v[0]); v0[1]=b2f((u16)v[1]); v0[2]=b2f((u16)v[2]); v0[3]=b2f((u16)v[3]);
        v1[0]=b2f((u16)v[4]); v1[1]=b2f((u16)v[5]); v1[2]=b2f((u16)v[6]); v1[3]=b2f((u16)v[7]);
      }
      float* dst = &Lp[pp*64 + lane8*8];
      *(f32x4*)dst = v0;
      *(f32x4*)(dst+4) = v1;
    }
  }
  const int c = tid & 63;
  const int yg = tid >> 6;  // 0..3
  float w[49];
  #pragma unroll
  for (int kt=0; kt<49; kt++) w[kt] = lwT[kt*256 + c0 + c];
  const float bias = lb[c0 + c];
  __syncthreads();
  #pragma unroll
  for (int half=0; half<2; half++){
    const int y = yg + half*4;
    float acc[8];
    #pragma unroll
    for (int xx=0;xx<8;xx++) acc[xx] = bias;
    #pragma unroll
    for (int ky=0;ky<7;ky++){
      const int prow = (y + ky)*14;
      float rv[14];
      #pragma unroll
      for (int xx=0;xx<14;xx++) rv[xx] = Lp[(prow + xx)*64 + c];
      #pragma unroll
      for (int kx=0;kx<7;kx++){
        float wv = w[ky*7+kx];
        #pragma unroll
        for (int xx=0;xx<8;xx++) acc[xx] = fmaf(wv, rv[xx+kx], acc[xx]);
      }
    }
    const int gy = ty*8 + y;
    size_t base = ((size_t)b*NTOK + gy*HH + tx*8)*256 + c0 + c;
    #pragma unroll
    for (int xx=0;xx<8;xx++) lepe[base + (size_t)xx*256] = f2b(acc[xx]);
  }
}

// ---------------- kernel 6: attention, 1 wave/block, ZERO LDS, raw v_exp_f32 ----------------
// Swapped QK^T (S^T = mfma(K,Q)) -> lane holds 16 P-values for ONE query (keys nf*16+lh*4+r).
// With vwt's kappa permutation those 16 values ARE the lane's two PV A-fragments.
__global__ __launch_bounds__(64, 3) void k_attn(const u16* __restrict__ qb, const u16* __restrict__ kb,
    const u16* __restrict__ vwt, const int* __restrict__ ridx,
    const u16* __restrict__ lepe, u16* __restrict__ ao){
  const int blk = blockIdx.x;
  const int h = blk & 7, bp = blk >> 3;
  const int b = bp/169, p = bp%169;
  const int wy = p/13, wx = p%13;
  const int l = threadIdx.x, l15 = l&15, lh = l>>4;
  const int rowoff = (l15>>3)*HH + (l15&7);

  s16x8 qf[4];
  {
    const u16* qbase = qb + ((size_t)b*NTOK + (wy*8)*HH + wx*8 + rowoff)*256 + h*32 + lh*8;
    #pragma unroll
    for (int mf=0;mf<4;mf++) qf[mf] = *(const s16x8*)(qbase + (size_t)mf*2*HH*256);
  }
  f32x4 o[4][2];
  f32x4 lsum4[4];
  #pragma unroll
  for (int mf=0;mf<4;mf++){
    o[mf][0] = (f32x4){0.f,0.f,0.f,0.f};
    o[mf][1] = (f32x4){0.f,0.f,0.f,0.f};
    lsum4[mf] = (f32x4){0.f,0.f,0.f,0.f};
  }

  const int* rp = ridx + bp*10;
  int win = rp[0];
  for (int t=0;t<10;t++){
    int wnext = (t<9) ? rp[t+1] : 0;     // prefetch next window index (off-chain)
    if ((unsigned)win > 168u) win = 0;
    int vy = win/13, vx = win - vy*13;
    const u16* kbase = kb + ((size_t)b*NTOK + (vy*8)*HH + vx*8 + rowoff)*256 + h*32 + lh*8;
    s16x8 kf[4];
    #pragma unroll
    for (int nf=0;nf<4;nf++) kf[nf] = *(const s16x8*)(kbase + (size_t)nf*2*HH*256);
    const u16* vbase = vwt + ((size_t)(b*169 + win)*256 + h*32 + l15)*64 + lh*8;
    s16x8 vf[2][2];
    #pragma unroll
    for (int d=0;d<2;d++)
      #pragma unroll
      for (int ks=0;ks<2;ks++)
        vf[d][ks] = *(const s16x8*)(vbase + d*1024 + ks*32);

    #pragma unroll
    for (int mf=0;mf<4;mf++){
      f32x4 s0 = mfma16(kf[0], qf[mf], (f32x4){0.f,0.f,0.f,0.f});
      f32x4 s1 = mfma16(kf[1], qf[mf], (f32x4){0.f,0.f,0.f,0.f});
      f32x4 s2 = mfma16(kf[2], qf[mf], (f32x4){0.f,0.f,0.f,0.f});
      f32x4 s3 = mfma16(kf[3], qf[mf], (f32x4){0.f,0.f,0.f,0.f});
      f32x4 e0, e1, e2, e3;
      #pragma unroll
      for (int j=0;j<4;j++){
        e0[j] = EXP2(s0[j]);
        e1[j] = EXP2(s1[j]);
        e2[j] = EXP2(s2[j]);
        e3[j] = EXP2(s3[j]);
      }
      lsum4[mf] += (e0+e1)+(e2+e3);
      // pack P into the two A-fragments via HW cvt (compiler emits v_cvt_pk_bf16_f32)
      s16x8 p0, p1;
      #pragma unroll
      for (int j=0;j<4;j++){
        p0[j]   = f2bs(e0[j]);
        p0[4+j] = f2bs(e1[j]);
        p1[j]   = f2bs(e2[j]);
        p1[4+j] = f2bs(e3[j]);
      }
      o[mf][0] = mfma16(p0, vf[0][0], o[mf][0]);
      o[mf][0] = mfma16(p1, vf[0][1], o[mf][0]);
      o[mf][1] = mfma16(p0, vf[1][0], o[mf][1]);
      o[mf][1] = mfma16(p1, vf[1][1], o[mf][1]);
    }
    win = wnext;
  }
  // epilogue: lane holds denom partial for query mf*16+l15; outputs are query lh*4+r
  #pragma unroll
  for (int mf=0;mf<4;mf++){
    float tot = (lsum4[mf][0]+lsum4[mf][1]) + (lsum4[mf][2]+lsum4[mf][3]);
    tot += __shfl_xor(tot,16);
    tot += __shfl_xor(tot,32);
    #pragma unroll
    for (int r=0;r<4;r++){
      float inv = 1.f/__shfl(tot, lh*4+r);
      int qr = mf*16 + lh*4 + r;
      int n = (wy*8 + (qr>>3))*HH + wx*8 + (qr&7);
      size_t base = ((size_t)b*NTOK + n)*256 + h*32;
      ao[base +      l15] = (u16)f2bs(o[mf][0][r]*inv + b2f(lepe[base +      l15]));
      ao[base + 16 + l15] = (u16)f2bs(o[mf][1][r]*inv + b2f(lepe[base + 16 + l15]));
    }
  }
}

// ---------------- kernel 7: out = ao @ Wo + bo ----------------
__global__ __launch_bounds__(256) void k_final(const u16* __restrict__ ao,
    const u16* __restrict__ woT, const float* __restrict__ bo, float* __restrict__ out){
  __shared__ __align__(16) short As[128][72];
  __shared__ __align__(16) short Bs[128][72];
  const int m0 = blockIdx.x*128, n0 = blockIdx.y*128;
  const int tid = threadIdx.x, wv = tid>>6, l = tid&63;
  const int wm = (wv>>1)*64, wn = (wv&1)*64;
  const int l15 = l&15, lh = l>>4;
  f32x4 acc[4][4];
  #pragma unroll
  for (int mf=0;mf<4;mf++)
    #pragma unroll
    for (int nf=0;nf<4;nf++) acc[mf][nf] = (f32x4){0.f,0.f,0.f,0.f};

  for (int kk=0; kk<256; kk+=64){
    __syncthreads();
    #pragma unroll
    for (int i=0;i<4;i++){
      int sid = i*256 + tid; int r = sid>>3, cu = (sid&7)*8;
      *(s16x8*)&As[r][cu] = *(const s16x8*)(ao  + (size_t)(m0+r)*256 + kk + cu);
      *(s16x8*)&Bs[r][cu] = *(const s16x8*)(woT + (size_t)(n0+r)*256 + kk + cu);
    }
    __syncthreads();
    #pragma unroll
    for (int ks=0; ks<2; ks++){
      s16x8 af[4], bf[4];
      #pragma unroll
      for (int mf=0; mf<4; mf++) af[mf] = *(const s16x8*)&As[wm+mf*16+l15][ks*32 + lh*8];
      #pragma unroll
      for (int nf=0; nf<4; nf++) bf[nf] = *(const s16x8*)&Bs[wn+nf*16+l15][ks*32 + lh*8];
      #pragma unroll
      for (int mf=0; mf<4; mf++)
        #pragma unroll
        for (int nf=0; nf<4; nf++)
          acc[mf][nf] = mfma16(af[mf], bf[nf], acc[mf][nf]);
    }
  }
  #pragma unroll
  for (int mf=0; mf<4; mf++)
    #pragma unroll
    for (int nf=0; nf<4; nf++){
      int gcol = n0 + wn + nf*16 + l15;
      float bv = bo[gcol];
      #pragma unroll
      for (int r=0;r<4;r++){
        int row = m0 + wm + mf*16 + lh*4 + r;
        out[(size_t)row*256 + gcol] = acc[mf][nf][r] + bv;
      }
    }
}

extern "C" void kernel_launch(void* const* d_in, const int* in_sizes, int n_in,
                              void* d_out, int out_size, void* d_ws, size_t ws_size,
                              hipStream_t stream){
  (void)in_sizes; (void)n_in; (void)out_size;
  if (ws_size < WS_NEEDED) return;
  const float* x    = (const float*)d_in[0];
  const float* Wqkv = (const float*)d_in[1];
  const float* bqkv = (const float*)d_in[2];
  const float* Wo   = (const float*)d_in[3];
  const float* bo   = (const float*)d_in[4];
  const float* lw   = (const float*)d_in[5];
  const float* lb   = (const float*)d_in[6];
  char* ws = (char*)d_ws;
  u16*   wqkvT = (u16*)(ws + OFF_WQKVT);
  u16*   woT   = (u16*)(ws + OFF_WOT);
  float* lwT   = (float*)(ws + OFF_LWT);
  u16*   qbf   = (u16*)(ws + OFF_QBF);
  u16*   kbf   = (u16*)(ws + OFF_KBF);
  u16*   vbf   = (u16*)(ws + OFF_VBF);
  u16*   vwt   = (u16*)(ws + OFF_VWT);
  float* qwin  = (float*)(ws + OFF_QWIN);
  float* kwin  = (float*)(ws + OFF_KWIN);
  int*   ridx  = (int*)(ws + OFF_RIDX);
  u16*   xbf   = (u16*)(ws + OFF_XBF);
  u16*   ao    = (u16*)(ws + OFF_AO);
  u16*   lepe  = (u16*)(ws + OFF_LEPE);
  float* out   = (float*)d_out;

  k_prep   <<<1073, 256, 0, stream>>>(Wqkv, Wo, lw, wqkvT, woT, lwT);
  k_winproj<<<338, 256, 0, stream>>>(x, Wqkv, bqkv, qwin, kwin, xbf);
  k_qkv    <<<dim3(169,6), 256, 0, stream>>>(xbf, wqkvT, bqkv, qbf, kbf, vbf);
  k_vt     <<<1352, 256, 0, stream>>>(vbf, vwt);
  k_router <<<338, 256, 0, stream>>>(qwin, kwin, ridx);
  k_conv   <<<1352, 256, 0, stream>>>(vbf, lwT, lb, lepe);
  k_attn   <<<2704, 64, 0, stream>>>(qbf, kbf, vwt, ridx, lepe, ao);
  k_final  <<<dim3(169,2), 256, 0, stream>>>(ao, woT, bo, out);
}